// Round 7
// baseline (1289.269 us; speedup 1.0000x reference)
//
#include <hip/hip_runtime.h>

#define N_TOK 16384   // B*T = 8*2048
#define DIM   512
#define CBD   256     // codebook dim
#define CBS   8192    // codebook size

typedef short short8 __attribute__((ext_vector_type(8)));
typedef float f32x4 __attribute__((ext_vector_type(4)));

#define GLOAD16(g, l) __builtin_amdgcn_global_load_lds( \
    (const __attribute__((address_space(1))) void*)(g), \
    (__attribute__((address_space(3))) void*)(l), 16, 0, 0)

#define SBAR() do { asm volatile("" ::: "memory"); \
                    __builtin_amdgcn_s_barrier();  \
                    asm volatile("" ::: "memory"); } while (0)
#define LGKM0() asm volatile("s_waitcnt lgkmcnt(0)" ::: "memory")
#define VMCNT(n) asm volatile("s_waitcnt vmcnt(" #n ")" ::: "memory")
#define PRIO1() __builtin_amdgcn_s_setprio(1)
#define PRIO0() __builtin_amdgcn_s_setprio(0)

__device__ inline unsigned short f2bf_rne(float f) {
    unsigned u = __float_as_uint(f);
    unsigned r = (u + 0x7FFFu + ((u >> 16) & 1u)) >> 16;
    return (unsigned short)r;
}
__device__ inline float bf2f(unsigned short h) { return __uint_as_float((unsigned)h << 16); }

// ================= packing: 2-term split [hi(K) | lo(K)] per row ==============
template <int LOGK>
__global__ __launch_bounds__(256) void pack_w(const float* __restrict__ src, short* __restrict__ dst) {
    int e = blockIdx.x * 256 + threadIdx.x;
    int r = e >> LOGK, k = e & ((1 << LOGK) - 1);
    float v = src[e];
    unsigned short h = f2bf_rne(v);
    unsigned short l = f2bf_rne(v - bf2f(h));
    size_t base = (size_t)r << (LOGK + 1);
    dst[base + k] = (short)h;
    dst[base + (1 << LOGK) + k] = (short)l;
}

// fused: e_sq (exact f32) + 2-term embed pack
__global__ __launch_bounds__(256) void prep_embed(const float* __restrict__ embed,
                                                  float* __restrict__ esq,
                                                  short* __restrict__ epack) {
    int wave = threadIdx.x >> 6, lane = threadIdx.x & 63;
    int c = (blockIdx.x << 2) + wave;
    float4 v = reinterpret_cast<const float4*>(embed + (size_t)c * CBD)[lane];
    short4 hs, ls;
    {
        unsigned short h, l;
        h = f2bf_rne(v.x); l = f2bf_rne(v.x - bf2f(h)); hs.x = h; ls.x = l;
        h = f2bf_rne(v.y); l = f2bf_rne(v.y - bf2f(h)); hs.y = h; ls.y = l;
        h = f2bf_rne(v.z); l = f2bf_rne(v.z - bf2f(h)); hs.z = h; ls.z = l;
        h = f2bf_rne(v.w); l = f2bf_rne(v.w - bf2f(h)); hs.w = h; ls.w = l;
    }
    reinterpret_cast<short4*>(epack + (size_t)c * 512)[lane] = hs;
    reinterpret_cast<short4*>(epack + (size_t)c * 512 + 256)[lane] = ls;
    float s = v.x * v.x + v.y * v.y + v.z * v.z + v.w * v.w;
    #pragma unroll
    for (int m = 32; m; m >>= 1) s += __shfl_xor(s, m, 64);
    if (!lane) esq[c] = s;
}

// ---- znorm: ||z_r|| (from zh half of zpack; 1.03 inflation in B covers) ----
__global__ __launch_bounds__(256) void znorm_k(const short* __restrict__ zpk,
                                               float* __restrict__ znorm) {
    int wave = threadIdx.x >> 6, lane = threadIdx.x & 63;
    int r = blockIdx.x * 4 + wave;
    short4 h = reinterpret_cast<const short4*>(zpk + (size_t)r * 512)[lane];
    float a = bf2f((unsigned short)h.x), b = bf2f((unsigned short)h.y);
    float c = bf2f((unsigned short)h.z), d = bf2f((unsigned short)h.w);
    float s = a * a + b * b + c * c + d * d;
    #pragma unroll
    for (int m = 32; m; m >>= 1) s += __shfl_xor(s, m, 64);
    if (!lane) znorm[r] = sqrtf(s);
}

// ---- maxE = max_c ||e_c|| ----
__global__ __launch_bounds__(256) void maxe_k(const float* __restrict__ esq,
                                              float* __restrict__ maxe) {
    float m = 0.f;
    #pragma unroll
    for (int k = 0; k < 32; ++k) m = fmaxf(m, esq[threadIdx.x + (k << 8)]);
    #pragma unroll
    for (int s = 32; s; s >>= 1) m = fmaxf(m, __shfl_xor(m, s, 64));
    __shared__ float w[4];
    if (!(threadIdx.x & 63)) w[threadIdx.x >> 6] = m;
    __syncthreads();
    if (threadIdx.x == 0)
        maxe[0] = sqrtf(fmaxf(fmaxf(w[0], w[1]), fmaxf(w[2], w[3])));
}

// ============ gemm_in: z = x@W_in^T + b_in, 4-term split-bf16, BM=64 BN=128 ===
__global__ __launch_bounds__(256, 3) void gemm_in_mfma(const short* __restrict__ xpk,
                                                       const short* __restrict__ wpk,
                                                       const float* __restrict__ b_in,
                                                       short* __restrict__ zpack) {
    __shared__ __align__(16) char smem[49152];
    const int tid = threadIdx.x;
    const int lane = tid & 63, wid = tid >> 6;
    const int l15 = lane & 15, rg = lane >> 4;
    const int bm = blockIdx.x << 6, bn = blockIdx.y << 7;
    const int g = tid & 7, rpb = tid >> 3;

    const char* xb = (const char*)xpk;
    const char* wb = (const char*)wpk;
    const int sw = ((g ^ (rpb & 7)) << 4);
    size_t aoff[2], boff[2][2];
    #pragma unroll
    for (int it = 0; it < 2; ++it)
        aoff[it] = (size_t)(bm + it * 32 + rpb) * 2048 + sw;
    #pragma unroll
    for (int it = 0; it < 4; ++it)
        boff[it >> 1][it & 1] = (size_t)(bn + it * 32 + rpb) * 2048 + sw;

    const int ax0 = ((rg ^ (l15 & 7)) << 4);
    const int ax1 = (((rg + 4) ^ (l15 & 7)) << 4);
    const char* aBase = smem + l15 * 128;
    const char* bBase = smem + 8192 + (wid * 32 + l15) * 128;

    f32x4 acc[4][2] = {};

#define GIN_STAGE(BUF, KT) do { \
    size_t aK = (size_t)(((((KT) >> 4) << 3) | ((KT) & 7))) * 128; \
    size_t bK = (size_t)((((((KT) >> 3) & 1) << 3) | ((KT) & 7))) * 128; \
    char* dA = smem + (BUF) * 24576 + (tid << 4); \
    char* dB = dA + 8192; \
    GLOAD16(xb + aoff[0] + aK, dA); \
    GLOAD16(xb + aoff[1] + aK, dA + 4096); \
    GLOAD16(wb + boff[0][0] + bK, dB); \
    GLOAD16(wb + boff[0][1] + bK, dB + 4096); \
    GLOAD16(wb + boff[1][0] + bK, dB + 8192); \
    GLOAD16(wb + boff[1][1] + bK, dB + 12288); } while (0)

    GIN_STAGE(0, 0);
    VMCNT(0);
    __syncthreads();
    #pragma unroll 1
    for (int kt = 0; kt < 32; ++kt) {
        const int buf = kt & 1;
        if (kt + 1 < 32) GIN_STAGE(buf ^ 1, kt + 1);
        const char* aB = aBase + buf * 24576;
        const char* bB = bBase + buf * 24576;
        #pragma unroll
        for (int ks = 0; ks < 2; ++ks) {
            int ax = ks ? ax1 : ax0;
            short8 aF[4], bF[2];
            #pragma unroll
            for (int mi = 0; mi < 4; ++mi) aF[mi] = *(const short8*)(aB + mi * 2048 + ax);
            #pragma unroll
            for (int ni = 0; ni < 2; ++ni) bF[ni] = *(const short8*)(bB + ni * 2048 + ax);
            #pragma unroll
            for (int mi = 0; mi < 4; ++mi)
                #pragma unroll
                for (int ni = 0; ni < 2; ++ni)
                    acc[mi][ni] = __builtin_amdgcn_mfma_f32_16x16x32_bf16(aF[mi], bF[ni], acc[mi][ni], 0, 0, 0);
        }
        VMCNT(0);
        __syncthreads();
    }
    float bb[2];
    #pragma unroll
    for (int ni = 0; ni < 2; ++ni) bb[ni] = b_in[bn + wid * 32 + ni * 16 + l15];
    #pragma unroll
    for (int mi = 0; mi < 4; ++mi)
        #pragma unroll
        for (int ni = 0; ni < 2; ++ni)
            #pragma unroll
            for (int j = 0; j < 4; ++j) {
                int r = bm + mi * 16 + rg * 4 + j;
                int c = bn + wid * 32 + ni * 16 + l15;
                float s = acc[mi][ni][j] + bb[ni];
                unsigned short zh = f2bf_rne(s);
                unsigned short zl = f2bf_rne(s - bf2f(zh));
                zpack[(size_t)r * 512 + c] = (short)zh;
                zpack[(size_t)r * 512 + 256 + c] = (short)zl;
            }
}

// ===== score1: 256x256, K=256 (4 kt of 64), 1-term bf16 (zh·eh), top-2 epilogue
// Rigor via B_r bound + rescue (see combine/rescue). Chunks: A/B chunk = kt (0..3).
__global__ __launch_bounds__(512, 2) void score_mfma(const short* __restrict__ zpk,
                                                     const short* __restrict__ epk,
                                                     const float* __restrict__ esqg,
                                                     float4* __restrict__ partials) {
    __shared__ __align__(16) char smem[131072];
    const int tid = threadIdx.x;
    const int lane = tid & 63, wid = tid >> 6;
    const int wr = wid >> 2, wc = wid & 3;
    const int l15 = lane & 15, rg = lane >> 4;

    int flat = blockIdx.x;
    int xcd = flat & 7, ix = flat >> 3;
    int bX = xcd * 8 + (ix & 7), bY = ix >> 3;
    const int bm = bX << 8, bn = bY << 8;
    const size_t bmB = (size_t)bX << 18;
    const size_t bnB = (size_t)bY << 18;

    const char* zb = (const char*)zpk;
    const char* eb = (const char*)epk;
    const int g = tid & 7, rp0 = tid >> 3;
    const size_t arow = (size_t)rp0 * 1024 + ((g ^ (rp0 & 7)) << 4);

#define SC_STAGE_A(BUF, H, KT) do { \
    const char* s_ = zb + bmB + (size_t)(H) * 131072 + (size_t)(KT) * 128 + arow; \
    char* d_ = smem + (BUF) * 32768 + (H) * 16384 + (tid << 4); \
    GLOAD16(s_, d_); GLOAD16(s_ + 65536, d_ + 8192); } while (0)
#define SC_STAGE_B(BUF, H, KT) do { \
    const char* s_ = eb + bnB + (size_t)(H) * 131072 + (size_t)(KT) * 128 + arow; \
    char* d_ = smem + 65536 + (BUF) * 32768 + (H) * 16384 + (tid << 4); \
    GLOAD16(s_, d_); GLOAD16(s_ + 65536, d_ + 8192); } while (0)

    const int ax0 = ((rg ^ (l15 & 7)) << 4);
    const int ax1 = (((rg + 4) ^ (l15 & 7)) << 4);
    const char* aBase = smem + wr * 16384 + l15 * 128;
    const char* bBase = smem + 65536 + (wc >> 1) * 16384 + ((wc & 1) * 64 + l15) * 128;

#define RD_A4(DST, BUF, MIB, AXR) { _Pragma("unroll") for (int mi_ = 0; mi_ < 4; ++mi_) \
    DST[mi_] = *(const short8*)(aBase + (BUF) * 32768 + ((MIB) + mi_) * 2048 + (AXR)); }
#define RD_B4(DST, BUF, AXR) { _Pragma("unroll") for (int ni_ = 0; ni_ < 4; ++ni_) \
    DST[ni_] = *(const short8*)(bBase + (BUF) * 32768 + ni_ * 2048 + (AXR)); }
#define MM16(R0, AF, BF) { _Pragma("unroll") for (int mi_ = 0; mi_ < 4; ++mi_) { \
    _Pragma("unroll") for (int ni_ = 0; ni_ < 4; ++ni_) \
      acc[(R0) + mi_][ni_] = __builtin_amdgcn_mfma_f32_16x16x32_bf16(AF[mi_], BF[ni_], acc[(R0) + mi_][ni_], 0, 0, 0); } }

    f32x4 acc[8][4] = {};

    // prologue: kt0 -> buf0, kt1 -> buf1
    SC_STAGE_A(0, 0, 0); SC_STAGE_A(0, 1, 0); SC_STAGE_B(0, 0, 0); SC_STAGE_B(0, 1, 0);
    SC_STAGE_A(1, 0, 1); SC_STAGE_A(1, 1, 1); SC_STAGE_B(1, 0, 1); SC_STAGE_B(1, 1, 1);
    VMCNT(8);
    SBAR();

    // per-kt: 4 phases; stage A(t+2) in NEXT kt's ph1, stage B(t+2) in ph4
    // (both only after the target buffer region's reads have fully completed).
#define SC_KT(BUF, PH1STG, PH4STG, VMW) do { \
    short8 aF[4], aG[4], bF[4]; \
    RD_A4(aF, BUF, 0, ax0); RD_B4(bF, BUF, ax0); \
    PH1STG; \
    SBAR(); LGKM0(); PRIO1(); MM16(0, aF, bF); PRIO0(); SBAR(); \
    RD_A4(aG, BUF, 4, ax0); \
    SBAR(); LGKM0(); PRIO1(); MM16(4, aG, bF); PRIO0(); SBAR(); \
    RD_A4(aF, BUF, 0, ax1); RD_B4(bF, BUF, ax1); \
    SBAR(); LGKM0(); PRIO1(); MM16(0, aF, bF); PRIO0(); SBAR(); \
    RD_A4(aG, BUF, 4, ax1); \
    PH4STG; \
    SBAR(); LGKM0(); PRIO1(); MM16(4, aG, bF); PRIO0(); \
    VMW; SBAR(); \
} while (0)

    SC_KT(0, ,
          { SC_STAGE_B(0, 0, 2); SC_STAGE_B(0, 1, 2); },
          VMCNT(4));
    SC_KT(1, { SC_STAGE_A(0, 0, 2); SC_STAGE_A(0, 1, 2); },
          { SC_STAGE_B(1, 0, 3); SC_STAGE_B(1, 1, 3); },
          VMCNT(4));
    SC_KT(0, { SC_STAGE_A(1, 0, 3); SC_STAGE_A(1, 1, 3); },
          ,
          VMCNT(0));
    SC_KT(1, , , );

    // epilogue: per-row top-2 of s = 2*acc - e_sq; 2-step shfl, 4 partials/row/wave
    float4* sRed = (float4*)smem;   // [8 waves][128 rows][4 groups] = 64KB
    const int cbase = bn + wc * 64 + l15;
    float esq4[4];
    #pragma unroll
    for (int ni = 0; ni < 4; ++ni) esq4[ni] = esqg[cbase + ni * 16];

    #pragma unroll
    for (int mi = 0; mi < 8; ++mi) {
        #pragma unroll
        for (int j = 0; j < 4; ++j) {
            float v1 = -3.4e38f, v2 = -3.4e38f;
            int i1 = 0x7fffffff;
            #pragma unroll
            for (int ni = 0; ni < 4; ++ni) {
                float s = fmaf(2.0f, acc[mi][ni][j], -esq4[ni]);
                int c = cbase + ni * 16;
                if (s > v1) { v2 = v1; v1 = s; i1 = c; }
                else if (s > v2) v2 = s;
            }
            #pragma unroll
            for (int m = 1; m < 4; m <<= 1) {
                float ov1 = __shfl_xor(v1, m, 64);
                int   oi1 = __shfl_xor(i1, m, 64);
                float ov2 = __shfl_xor(v2, m, 64);
                float nv2 = fmaxf(fmaxf(v2, ov2), fminf(v1, ov1));
                if (ov1 > v1 || (ov1 == v1 && oi1 < i1)) { v1 = ov1; i1 = oi1; }
                v2 = nv2;
            }
            if ((l15 & 3) == 0)
                sRed[(((wid << 7) + mi * 16 + rg * 4 + j) << 2) + (l15 >> 2)] =
                    make_float4(v1, __int_as_float(i1), v2, 0.f);
        }
    }
    __syncthreads();
    if (wc < 2) {
        int row = (wc << 6) + lane;
        float v1 = -3.4e38f, v2 = -3.4e38f; int i1 = 0x7fffffff;
        #pragma unroll
        for (int q = 0; q < 4; ++q)
            #pragma unroll
            for (int gq = 0; gq < 4; ++gq) {
                float4 e = sRed[(((((wr << 2) + q) << 7) + row) << 2) + gq];
                float w1 = e.x; int jx = __float_as_int(e.y);
                float nv2 = fmaxf(fmaxf(v2, e.z), fminf(v1, w1));
                if (w1 > v1 || (w1 == v1 && jx < i1)) { v1 = w1; i1 = jx; }
                v2 = nv2;
            }
        int grow = bm + (wr << 7) + row;
        partials[(size_t)grow * 32 + bY] = make_float4(v1, __int_as_float(i1), v2, 0.f);
    }
}

// -------- combine: global top-2 + rigorous rescue decision (gap <= 2*B_r) -----
// B_r = 2^-7 * ||z_r|| * maxE (bf16 cross-term bound), inflated 1.03x + 0.05.
__global__ __launch_bounds__(256) void combine(const float4* __restrict__ partials,
                                               const float* __restrict__ znorm,
                                               const float* __restrict__ maxe,
                                               int* __restrict__ idx, float* __restrict__ idxf,
                                               float* __restrict__ rescueT) {
    int sub = threadIdx.x & 31;
    int row = blockIdx.x * 8 + (threadIdx.x >> 5);
    float4 p = partials[(size_t)row * 32 + sub];
    float v1 = p.x; int i1 = __float_as_int(p.y); float v2 = p.z;
    #pragma unroll
    for (int m = 1; m < 32; m <<= 1) {
        float ov1 = __shfl_xor(v1, m, 64);
        int   oi1 = __shfl_xor(i1, m, 64);
        float ov2 = __shfl_xor(v2, m, 64);
        float nv2 = fmaxf(fmaxf(v2, ov2), fminf(v1, ov1));
        if (ov1 > v1 || (ov1 == v1 && oi1 < i1)) { v1 = ov1; i1 = oi1; }
        v2 = nv2;
    }
    if (sub == 0) {
        float B = fmaf(0.00805f * maxe[0], znorm[row], 0.05f);
        float thr = 2.0f * B;
        idx[row] = i1;
        idxf[row] = (float)i1;
        rescueT[row] = (v1 - v2 <= thr) ? (v1 - thr) : 3.0e38f;
    }
}

// ---- exact rescue: recompute z-row from x (exact f32), rescan candidate tiles
__global__ __launch_bounds__(256) void rescue(const float* __restrict__ x,
                                              const float* __restrict__ W_in,
                                              const float* __restrict__ b_in,
                                              const float* __restrict__ embed,
                                              const float* __restrict__ esq,
                                              const float4* __restrict__ partials,
                                              const float* __restrict__ rescueT,
                                              int* __restrict__ idx, float* __restrict__ idxf) {
    int row = blockIdx.x;
    float t = rescueT[row];
    if (t > 1.0e38f) return;
    __shared__ __align__(16) float xrow[512];
    __shared__ __align__(16) float zrow[256];
    __shared__ float sv[256];
    __shared__ int   si[256];
    const int tid = threadIdx.x;
    xrow[tid] = x[(size_t)row * 512 + tid];
    xrow[tid + 256] = x[(size_t)row * 512 + 256 + tid];
    __syncthreads();
    {
        float d = b_in[tid];
        const float4* wr4 = (const float4*)(W_in + (size_t)tid * 512);
        const float4* xr4 = (const float4*)xrow;
        #pragma unroll 8
        for (int k = 0; k < 128; ++k) {
            float4 w4 = wr4[k], x4 = xr4[k];
            d = fmaf(w4.x, x4.x, d); d = fmaf(w4.y, x4.y, d);
            d = fmaf(w4.z, x4.z, d); d = fmaf(w4.w, x4.w, d);
        }
        zrow[tid] = d;
    }
    __syncthreads();
    float bv = -3.4e38f; int bi = 0x7fffffff;
    for (int nt = 0; nt < 32; ++nt) {
        if (partials[(size_t)row * 32 + nt].x < t) continue;  // block-uniform
        int c = nt * 256 + tid;
        const float4* er = (const float4*)(embed + (size_t)c * 256);
        const float4* zr = (const float4*)zrow;
        float d = 0.f;
        #pragma unroll 4
        for (int k = 0; k < 64; ++k) {
            float4 e4 = er[k], z4 = zr[k];
            d = fmaf(e4.x, z4.x, d); d = fmaf(e4.y, z4.y, d);
            d = fmaf(e4.z, z4.z, d); d = fmaf(e4.w, z4.w, d);
        }
        float s = 2.f * d - esq[c];
        if (s > bv || (s == bv && c < bi)) { bv = s; bi = c; }
    }
    sv[tid] = bv; si[tid] = bi;
    __syncthreads();
    for (int s = 128; s; s >>= 1) {
        if (tid < s) {
            float ov = sv[tid + s]; int oi = si[tid + s];
            if (ov > sv[tid] || (ov == sv[tid] && oi < si[tid])) { sv[tid] = ov; si[tid] = oi; }
        }
        __syncthreads();
    }
    if (tid == 0) { idx[row] = si[0]; idxf[row] = (float)si[0]; }
}

// ====== gemm_out: out = embed[idx]@W_out^T + b_out, 4-term, BM=128 BN=128 =====
__global__ __launch_bounds__(256, 2) void gemm_out_mfma(const short* __restrict__ epk,
                                                        const short* __restrict__ wpk,
                                                        const int* __restrict__ idx,
                                                        const float* __restrict__ b_out,
                                                        float* __restrict__ out) {
    __shared__ __align__(16) char smem[65536];
    const int tid = threadIdx.x;
    const int lane = tid & 63, wid = tid >> 6;
    const int wr = wid >> 1, wc = wid & 1;
    const int l15 = lane & 15, rg = lane >> 4;
    const int bm = blockIdx.x << 7, bn = blockIdx.y << 7;
    const int g = tid & 7, rpb = tid >> 3;

    const char* ebp = (const char*)epk;
    const char* wb = (const char*)wpk;
    const int sw = ((g ^ (rpb & 7)) << 4);
    size_t aoff[4], boff[4];
    #pragma unroll
    for (int it = 0; it < 4; ++it) {
        int c = idx[bm + it * 32 + rpb];
        aoff[it] = (size_t)c * 1024 + sw;
        boff[it] = (size_t)(bn + it * 32 + rpb) * 1024 + sw;
    }

    const int ax0 = ((rg ^ (l15 & 7)) << 4);
    const int ax1 = (((rg + 4) ^ (l15 & 7)) << 4);
    const char* aBase = smem + (wr * 64 + l15) * 128;
    const char* bBase = smem + 16384 + (wc * 64 + l15) * 128;

    f32x4 acc[4][4] = {};

#define GOUT_STAGE(BUF, KT) do { \
    size_t aK = (size_t)((((KT) & 3) | (((KT) >> 3) << 2))) * 128; \
    size_t bK = (size_t)((KT) & 7) * 128; \
    char* dA = smem + (BUF) * 32768 + (tid << 4); \
    char* dB = dA + 16384; \
    _Pragma("unroll") for (int it_ = 0; it_ < 4; ++it_) { \
        GLOAD16(ebp + aoff[it_] + aK, dA + it_ * 4096); \
        GLOAD16(wb + boff[it_] + bK, dB + it_ * 4096); } } while (0)

    GOUT_STAGE(0, 0);
    VMCNT(0);
    __syncthreads();
    #pragma unroll 1
    for (int kt = 0; kt < 16; ++kt) {
        const int buf = kt & 1;
        if (kt + 1 < 16) GOUT_STAGE(buf ^ 1, kt + 1);
        const char* aB = aBase + buf * 32768;
        const char* bB = bBase + buf * 32768;
        #pragma unroll
        for (int ks = 0; ks < 2; ++ks) {
            int ax = ks ? ax1 : ax0;
            short8 aF[4], bF[4];
            #pragma unroll
            for (int mi = 0; mi < 4; ++mi) aF[mi] = *(const short8*)(aB + mi * 2048 + ax);
            #pragma unroll
            for (int ni = 0; ni < 4; ++ni) bF[ni] = *(const short8*)(bB + ni * 2048 + ax);
            #pragma unroll
            for (int mi = 0; mi < 4; ++mi)
                #pragma unroll
                for (int ni = 0; ni < 4; ++ni)
                    acc[mi][ni] = __builtin_amdgcn_mfma_f32_16x16x32_bf16(aF[mi], bF[ni], acc[mi][ni], 0, 0, 0);
        }
        VMCNT(0);
        __syncthreads();
    }
    float bb[4];
    #pragma unroll
    for (int ni = 0; ni < 4; ++ni) bb[ni] = b_out[bn + wc * 64 + ni * 16 + l15];
    #pragma unroll
    for (int mi = 0; mi < 4; ++mi)
        #pragma unroll
        for (int ni = 0; ni < 4; ++ni)
            #pragma unroll
            for (int j = 0; j < 4; ++j) {
                int r = bm + wr * 64 + mi * 16 + rg * 4 + j;
                int c = bn + wc * 64 + ni * 16 + l15;
                out[(size_t)r * 512 + c] = acc[mi][ni][j] + bb[ni];
            }
}

// =================== fallback f32 path (ws too small) =========================
__global__ __launch_bounds__(256) void esq_kernel(const float* __restrict__ embed,
                                                  float* __restrict__ esq) {
    int wave = threadIdx.x >> 6, lane = threadIdx.x & 63;
    int c = (blockIdx.x << 2) + wave;
    float4 v = reinterpret_cast<const float4*>(embed + (size_t)c * CBD)[lane];
    float s = v.x * v.x + v.y * v.y + v.z * v.z + v.w * v.w;
    #pragma unroll
    for (int m = 32; m; m >>= 1) s += __shfl_xor(s, m, 64);
    if (!lane) esq[c] = s;
}

template <bool GATHER>
__global__ __launch_bounds__(256) void gemm_nt(const float* __restrict__ A,
                                               const float* __restrict__ B,
                                               const float* __restrict__ bias,
                                               const int* __restrict__ gather,
                                               float* __restrict__ C,
                                               int M, int N, int K) {
    __shared__ __align__(16) float sA[64][68];
    __shared__ __align__(16) float sB[64][68];
    const int tid = threadIdx.x;
    const int tx = tid & 15, ty = tid >> 4;
    const int bm = blockIdx.x << 6, bn = blockIdx.y << 6;
    float acc[4][4] = {};
    for (int k0 = 0; k0 < K; k0 += 64) {
        #pragma unroll
        for (int i = 0; i < 4; ++i) {
            int f = tid + (i << 8);
            int m = f >> 4;
            int k4 = (f & 15) << 2;
            long arow = bm + m;
            if (GATHER) arow = gather[arow];
            float4 v = *reinterpret_cast<const float4*>(A + arow * K + k0 + k4);
            sA[k4 + 0][m] = v.x; sA[k4 + 1][m] = v.y;
            sA[k4 + 2][m] = v.z; sA[k4 + 3][m] = v.w;
            float4 w = *reinterpret_cast<const float4*>(B + (long)(bn + m) * K + k0 + k4);
            sB[k4 + 0][m] = w.x; sB[k4 + 1][m] = w.y;
            sB[k4 + 2][m] = w.z; sB[k4 + 3][m] = w.w;
        }
        __syncthreads();
        #pragma unroll
        for (int kk = 0; kk < 64; ++kk) {
            float4 a = *reinterpret_cast<const float4*>(&sA[kk][ty << 2]);
            float4 b = *reinterpret_cast<const float4*>(&sB[kk][tx << 2]);
            float av[4] = {a.x, a.y, a.z, a.w};
            float bv[4] = {b.x, b.y, b.z, b.w};
            #pragma unroll
            for (int i = 0; i < 4; ++i)
                #pragma unroll
                for (int j = 0; j < 4; ++j)
                    acc[i][j] = fmaf(av[i], bv[j], acc[i][j]);
        }
        __syncthreads();
    }
    #pragma unroll
    for (int i = 0; i < 4; ++i) {
        long m = bm + (ty << 2) + i;
        #pragma unroll
        for (int j = 0; j < 4; ++j) {
            int n = bn + (tx << 2) + j;
            C[m * N + n] = acc[i][j] + bias[n];
        }
    }
}

__global__ __launch_bounds__(256) void score_argmax(const float* __restrict__ z,
                                                    const float* __restrict__ embed,
                                                    const float* __restrict__ esq,
                                                    int* __restrict__ idx_out,
                                                    float* __restrict__ idx_f32) {
    __shared__ __align__(16) float sZ[64][68];
    __shared__ __align__(16) float sE[64][68];
    const int tid = threadIdx.x;
    const int tx = tid & 15, ty = tid >> 4;
    const int bm = blockIdx.x << 6;
    float best[4];
    int bidx[4];
    #pragma unroll
    for (int i = 0; i < 4; ++i) { best[i] = -3.4e38f; bidx[i] = 0; }
    for (int ct = 0; ct < CBS; ct += 64) {
        float acc[4][4] = {};
        for (int k0 = 0; k0 < CBD; k0 += 64) {
            #pragma unroll
            for (int i = 0; i < 4; ++i) {
                int f = tid + (i << 8);
                int m = f >> 4;
                int k4 = (f & 15) << 2;
                float4 v = *reinterpret_cast<const float4*>(z + (long)(bm + m) * CBD + k0 + k4);
                sZ[k4 + 0][m] = v.x; sZ[k4 + 1][m] = v.y;
                sZ[k4 + 2][m] = v.z; sZ[k4 + 3][m] = v.w;
                float4 w = *reinterpret_cast<const float4*>(embed + (long)(ct + m) * CBD + k0 + k4);
                sB_DUMMY:;
                sE[k4 + 0][m] = w.x; sE[k4 + 1][m] = w.y;
                sE[k4 + 2][m] = w.z; sE[k4 + 3][m] = w.w;
            }
            __syncthreads();
            #pragma unroll
            for (int kk = 0; kk < 64; ++kk) {
                float4 a = *reinterpret_cast<const float4*>(&sZ[kk][ty << 2]);
                float4 b = *reinterpret_cast<const float4*>(&sE[kk][tx << 2]);
                float av[4] = {a.x, a.y, a.z, a.w};
                float bv[4] = {b.x, b.y, b.z, b.w};
                #pragma unroll
                for (int i = 0; i < 4; ++i)
                    #pragma unroll
                    for (int j = 0; j < 4; ++j)
                        acc[i][j] = fmaf(av[i], bv[j], acc[i][j]);
            }
            __syncthreads();
        }
        #pragma unroll
        for (int j = 0; j < 4; ++j) {
            int c = ct + (tx << 2) + j;
            float eq = esq[c];
            #pragma unroll
            for (int i = 0; i < 4; ++i) {
                float s = 2.0f * acc[i][j] - eq;
                if (s > best[i] || (s == best[i] && c < bidx[i])) { best[i] = s; bidx[i] = c; }
            }
        }
    }
    #pragma unroll
    for (int i = 0; i < 4; ++i) {
        float b = best[i];
        int bi = bidx[i];
        #pragma unroll
        for (int m = 1; m < 16; m <<= 1) {
            float ob = __shfl_xor(b, m, 64);
            int oi = __shfl_xor(bi, m, 64);
            if (ob > b || (ob == b && oi < bi)) { b = ob; bi = oi; }
        }
        if (tx == 0) {
            int row = bm + (ty << 2) + i;
            idx_out[row] = bi;
            idx_f32[row] = (float)bi;
        }
    }
}

extern "C" void kernel_launch(void* const* d_in, const int* in_sizes, int n_in,
                              void* d_out, int out_size, void* d_ws, size_t ws_size,
                              hipStream_t stream) {
    const float* x     = (const float*)d_in[0];
    const float* embed = (const float*)d_in[1];
    const float* W_in  = (const float*)d_in[2];
    const float* b_in  = (const float*)d_in[3];
    const float* W_out = (const float*)d_in[4];
    const float* b_out = (const float*)d_in[5];

    float* out_idx = (float*)d_out;              // [16384] indices as float
    float* out     = (float*)d_out + N_TOK;      // [16384,512]

    // workspace layout (main path)
    char* ws = (char*)d_ws;
    float*  esq      = (float*)ws;                                   // 32KB
    float*  rescueT  = (float*)(ws + 32768);                         // 64KB
    int*    idx      = (int*)(ws + 98304);                           // 64KB
    float*  znorm    = (float*)(ws + 163840);                        // 64KB
    float*  maxe     = (float*)(ws + 229376);                        // 256B
    float4* partials = (float4*)(ws + 229632);                       // 8MB
    short*  xpack    = (short*)(ws + 229632 + 8388608);              // 33.55MB
    short*  zpack    = xpack + (size_t)N_TOK * 1024;                 // 16.78MB
    short*  epack    = zpack + (size_t)N_TOK * 512;                  // 8.39MB
    short*  winpk    = epack + (size_t)CBS * 512;                    // 0.52MB
    short*  wopk     = winpk + (size_t)CBD * 1024;                   // 0.52MB
    size_t need = (size_t)((char*)(wopk + (size_t)DIM * 512) - ws);

    if (ws_size >= need) {
        pack_w<9><<<(N_TOK * DIM) / 256, 256, 0, stream>>>(x, xpack);
        pack_w<9><<<(CBD * DIM) / 256, 256, 0, stream>>>(W_in, winpk);
        pack_w<8><<<(DIM * CBD) / 256, 256, 0, stream>>>(W_out, wopk);
        prep_embed<<<CBS / 4, 256, 0, stream>>>(embed, esq, epack);
        maxe_k<<<1, 256, 0, stream>>>(esq, maxe);
        // z = x@W_in^T + b_in (4-term MFMA), writes packed z
        gemm_in_mfma<<<dim3(N_TOK / 64, 2), 256, 0, stream>>>(xpack, winpk, b_in, zpack);
        znorm_k<<<N_TOK / 4, 256, 0, stream>>>(zpack, znorm);
        // 1-term bf16 scores + per-tile top-2
        score_mfma<<<2048, 512, 0, stream>>>(zpack, epack, esq, partials);
        // combine -> idx + bound-based rescue thresholds
        combine<<<N_TOK / 8, 256, 0, stream>>>(partials, znorm, maxe, idx, out_idx, rescueT);
        // exact rescue (recomputes z exactly from x; scans candidate tiles)
        rescue<<<N_TOK, 256, 0, stream>>>(x, W_in, b_in, embed, esq, partials, rescueT, idx, out_idx);
        // out = embed[idx]@W_out^T + b_out
        gemm_out_mfma<<<dim3(N_TOK / 128, 4), 256, 0, stream>>>(epack, wopk, idx, b_out, out);
    } else {
        float* z   = (float*)d_ws;
        float* es  = z + (size_t)N_TOK * CBD;
        int*   id  = (int*)(es + CBS);
        gemm_nt<false><<<dim3(N_TOK / 64, CBD / 64), 256, 0, stream>>>(
            x, W_in, b_in, nullptr, z, N_TOK, CBD, DIM);
        esq_kernel<<<CBS / 4, 256, 0, stream>>>(embed, es);
        score_argmax<<<N_TOK / 64, 256, 0, stream>>>(z, embed, es, id, out_idx);
        gemm_nt<true><<<dim3(N_TOK / 64, DIM / 64), 256, 0, stream>>>(
            embed, W_out, b_out, id, out, N_TOK, DIM, CBD);
    }
}

// Round 8
// 464.856 us; speedup vs baseline: 2.7735x; 2.7735x over previous
//
#include <hip/hip_runtime.h>

#define N_TOK 16384   // B*T = 8*2048
#define DIM   512
#define CBD   256     // codebook dim
#define CBS   8192    // codebook size

typedef short short8 __attribute__((ext_vector_type(8)));
typedef float f32x4 __attribute__((ext_vector_type(4)));

#define GLOAD16(g, l) __builtin_amdgcn_global_load_lds( \
    (const __attribute__((address_space(1))) void*)(g), \
    (__attribute__((address_space(3))) void*)(l), 16, 0, 0)

#define SBAR() do { asm volatile("" ::: "memory"); \
                    __builtin_amdgcn_s_barrier();  \
                    asm volatile("" ::: "memory"); } while (0)
#define LGKM0() asm volatile("s_waitcnt lgkmcnt(0)" ::: "memory")
#define VMCNT(n) asm volatile("s_waitcnt vmcnt(" #n ")" ::: "memory")
#define PRIO1() __builtin_amdgcn_s_setprio(1)
#define PRIO0() __builtin_amdgcn_s_setprio(0)

__device__ inline unsigned short f2bf_rne(float f) {
    unsigned u = __float_as_uint(f);
    unsigned r = (u + 0x7FFFu + ((u >> 16) & 1u)) >> 16;
    return (unsigned short)r;
}
__device__ inline float bf2f(unsigned short h) { return __uint_as_float((unsigned)h << 16); }
__device__ inline short f2h(float f) {
    _Float16 h = (_Float16)f;           // v_cvt_f16_f32, RNE
    short r; __builtin_memcpy(&r, &h, 2); return r;
}

// ================= packing: 2-term split [hi(K) | lo(K)] per row ==============
template <int LOGK>
__global__ __launch_bounds__(256) void pack_w(const float* __restrict__ src, short* __restrict__ dst) {
    int e = blockIdx.x * 256 + threadIdx.x;
    int r = e >> LOGK, k = e & ((1 << LOGK) - 1);
    float v = src[e];
    unsigned short h = f2bf_rne(v);
    unsigned short l = f2bf_rne(v - bf2f(h));
    size_t base = (size_t)r << (LOGK + 1);
    dst[base + k] = (short)h;
    dst[base + (1 << LOGK) + k] = (short)l;
}

// fused: e_sq (exact f32) + 2-term bf16 embed pack (gemm_out) + 1-term f16 (score)
__global__ __launch_bounds__(256) void prep_embed(const float* __restrict__ embed,
                                                  float* __restrict__ esq,
                                                  short* __restrict__ epack,
                                                  short* __restrict__ e16) {
    int wave = threadIdx.x >> 6, lane = threadIdx.x & 63;
    int c = (blockIdx.x << 2) + wave;
    float4 v = reinterpret_cast<const float4*>(embed + (size_t)c * CBD)[lane];
    short4 hs, ls, fs;
    {
        unsigned short h, l;
        h = f2bf_rne(v.x); l = f2bf_rne(v.x - bf2f(h)); hs.x = h; ls.x = l;
        h = f2bf_rne(v.y); l = f2bf_rne(v.y - bf2f(h)); hs.y = h; ls.y = l;
        h = f2bf_rne(v.z); l = f2bf_rne(v.z - bf2f(h)); hs.z = h; ls.z = l;
        h = f2bf_rne(v.w); l = f2bf_rne(v.w - bf2f(h)); hs.w = h; ls.w = l;
    }
    fs.x = f2h(v.x); fs.y = f2h(v.y); fs.z = f2h(v.z); fs.w = f2h(v.w);
    reinterpret_cast<short4*>(epack + (size_t)c * 512)[lane] = hs;
    reinterpret_cast<short4*>(epack + (size_t)c * 512 + 256)[lane] = ls;
    reinterpret_cast<short4*>(e16 + (size_t)c * 256)[lane] = fs;
    float s = v.x * v.x + v.y * v.y + v.z * v.z + v.w * v.w;
    #pragma unroll
    for (int m = 32; m; m >>= 1) s += __shfl_xor(s, m, 64);
    if (!lane) esq[c] = s;
}

// ---- znorm: ||z_r|| from exact zf32 ----
__global__ __launch_bounds__(256) void znorm_k(const float* __restrict__ zf32,
                                               float* __restrict__ znorm) {
    int wave = threadIdx.x >> 6, lane = threadIdx.x & 63;
    int r = blockIdx.x * 4 + wave;
    float4 v = reinterpret_cast<const float4*>(zf32 + (size_t)r * 256)[lane];
    float s = v.x * v.x + v.y * v.y + v.z * v.z + v.w * v.w;
    #pragma unroll
    for (int m = 32; m; m >>= 1) s += __shfl_xor(s, m, 64);
    if (!lane) znorm[r] = sqrtf(s);
}

// ---- maxE = max_c ||e_c|| ----
__global__ __launch_bounds__(256) void maxe_k(const float* __restrict__ esq,
                                              float* __restrict__ maxe) {
    float m = 0.f;
    #pragma unroll
    for (int k = 0; k < 32; ++k) m = fmaxf(m, esq[threadIdx.x + (k << 8)]);
    #pragma unroll
    for (int s = 32; s; s >>= 1) m = fmaxf(m, __shfl_xor(m, s, 64));
    __shared__ float w[4];
    if (!(threadIdx.x & 63)) w[threadIdx.x >> 6] = m;
    __syncthreads();
    if (threadIdx.x == 0)
        maxe[0] = sqrtf(fmaxf(fmaxf(w[0], w[1]), fmaxf(w[2], w[3])));
}

// ============ gemm_in: z = x@W_in^T + b_in, 4-term split-bf16, BM=64 BN=128 ===
// Writes z16 (f16, for score) and zf32 (exact f32, for rescue).
__global__ __launch_bounds__(256, 3) void gemm_in_mfma(const short* __restrict__ xpk,
                                                       const short* __restrict__ wpk,
                                                       const float* __restrict__ b_in,
                                                       short* __restrict__ z16,
                                                       float* __restrict__ zf32) {
    __shared__ __align__(16) char smem[49152];
    const int tid = threadIdx.x;
    const int lane = tid & 63, wid = tid >> 6;
    const int l15 = lane & 15, rg = lane >> 4;
    const int bm = blockIdx.x << 6, bn = blockIdx.y << 7;
    const int g = tid & 7, rpb = tid >> 3;

    const char* xb = (const char*)xpk;
    const char* wb = (const char*)wpk;
    const int sw = ((g ^ (rpb & 7)) << 4);
    size_t aoff[2], boff[2][2];
    #pragma unroll
    for (int it = 0; it < 2; ++it)
        aoff[it] = (size_t)(bm + it * 32 + rpb) * 2048 + sw;
    #pragma unroll
    for (int it = 0; it < 4; ++it)
        boff[it >> 1][it & 1] = (size_t)(bn + it * 32 + rpb) * 2048 + sw;

    const int ax0 = ((rg ^ (l15 & 7)) << 4);
    const int ax1 = (((rg + 4) ^ (l15 & 7)) << 4);
    const char* aBase = smem + l15 * 128;
    const char* bBase = smem + 8192 + (wid * 32 + l15) * 128;

    f32x4 acc[4][2] = {};

#define GIN_STAGE(BUF, KT) do { \
    size_t aK = (size_t)(((((KT) >> 4) << 3) | ((KT) & 7))) * 128; \
    size_t bK = (size_t)((((((KT) >> 3) & 1) << 3) | ((KT) & 7))) * 128; \
    char* dA = smem + (BUF) * 24576 + (tid << 4); \
    char* dB = dA + 8192; \
    GLOAD16(xb + aoff[0] + aK, dA); \
    GLOAD16(xb + aoff[1] + aK, dA + 4096); \
    GLOAD16(wb + boff[0][0] + bK, dB); \
    GLOAD16(wb + boff[0][1] + bK, dB + 4096); \
    GLOAD16(wb + boff[1][0] + bK, dB + 8192); \
    GLOAD16(wb + boff[1][1] + bK, dB + 12288); } while (0)

    GIN_STAGE(0, 0);
    VMCNT(0);
    __syncthreads();
    #pragma unroll 1
    for (int kt = 0; kt < 32; ++kt) {
        const int buf = kt & 1;
        if (kt + 1 < 32) GIN_STAGE(buf ^ 1, kt + 1);
        const char* aB = aBase + buf * 24576;
        const char* bB = bBase + buf * 24576;
        #pragma unroll
        for (int ks = 0; ks < 2; ++ks) {
            int ax = ks ? ax1 : ax0;
            short8 aF[4], bF[2];
            #pragma unroll
            for (int mi = 0; mi < 4; ++mi) aF[mi] = *(const short8*)(aB + mi * 2048 + ax);
            #pragma unroll
            for (int ni = 0; ni < 2; ++ni) bF[ni] = *(const short8*)(bB + ni * 2048 + ax);
            #pragma unroll
            for (int mi = 0; mi < 4; ++mi)
                #pragma unroll
                for (int ni = 0; ni < 2; ++ni)
                    acc[mi][ni] = __builtin_amdgcn_mfma_f32_16x16x32_bf16(aF[mi], bF[ni], acc[mi][ni], 0, 0, 0);
        }
        VMCNT(0);
        __syncthreads();
    }
    float bb[2];
    #pragma unroll
    for (int ni = 0; ni < 2; ++ni) bb[ni] = b_in[bn + wid * 32 + ni * 16 + l15];
    #pragma unroll
    for (int mi = 0; mi < 4; ++mi)
        #pragma unroll
        for (int ni = 0; ni < 2; ++ni)
            #pragma unroll
            for (int j = 0; j < 4; ++j) {
                int r = bm + mi * 16 + rg * 4 + j;
                int c = bn + wid * 32 + ni * 16 + l15;
                float s = acc[mi][ni][j] + bb[ni];
                z16[(size_t)r * 256 + c] = f2h(s);
                zf32[(size_t)r * 256 + c] = s;
            }
}

// ===== score: 256x256, K=256 (4 kt of 64), 1-term FP16 (z16·e16), top-2 epilogue
// Rigor via B_r = 2*2^-10*||z||*maxE bound + exact rescue.
__global__ __launch_bounds__(512, 2) void score_mfma(const short* __restrict__ zpk,
                                                     const short* __restrict__ epk,
                                                     const float* __restrict__ esqg,
                                                     float4* __restrict__ partials) {
    __shared__ __align__(16) char smem[131072];
    const int tid = threadIdx.x;
    const int lane = tid & 63, wid = tid >> 6;
    const int wr = wid >> 2, wc = wid & 3;
    const int l15 = lane & 15, rg = lane >> 4;

    int flat = blockIdx.x;
    int xcd = flat & 7, ix = flat >> 3;
    int bX = xcd * 8 + (ix & 7), bY = ix >> 3;
    const int bm = bX << 8, bn = bY << 8;
    const size_t bmB = (size_t)bX << 17;         // rows*512B
    const size_t bnB = (size_t)bY << 17;

    const char* zb = (const char*)zpk;
    const char* eb = (const char*)epk;
    const int g = tid & 7, rp0 = tid >> 3;       // rp0 0..63
    const size_t arow = (size_t)rp0 * 512 + ((g ^ (rp0 & 7)) << 4);

#define SC_STAGE_A(BUF, H, KT) do { \
    const char* s_ = zb + bmB + (size_t)(H) * 65536 + (size_t)(KT) * 128 + arow; \
    char* d_ = smem + (BUF) * 32768 + (H) * 16384 + (tid << 4); \
    GLOAD16(s_, d_); GLOAD16(s_ + 32768, d_ + 8192); } while (0)
#define SC_STAGE_B(BUF, H, KT) do { \
    const char* s_ = eb + bnB + (size_t)(H) * 65536 + (size_t)(KT) * 128 + arow; \
    char* d_ = smem + 65536 + (BUF) * 32768 + (H) * 16384 + (tid << 4); \
    GLOAD16(s_, d_); GLOAD16(s_ + 32768, d_ + 8192); } while (0)

    const int ax0 = ((rg ^ (l15 & 7)) << 4);
    const int ax1 = (((rg + 4) ^ (l15 & 7)) << 4);
    const char* aBase = smem + wr * 16384 + l15 * 128;
    const char* bBase = smem + 65536 + (wc >> 1) * 16384 + ((wc & 1) * 64 + l15) * 128;

#define RD_A4(DST, BUF, MIB, AXR) { _Pragma("unroll") for (int mi_ = 0; mi_ < 4; ++mi_) \
    DST[mi_] = *(const short8*)(aBase + (BUF) * 32768 + ((MIB) + mi_) * 2048 + (AXR)); }
#define RD_B4(DST, BUF, AXR) { _Pragma("unroll") for (int ni_ = 0; ni_ < 4; ++ni_) \
    DST[ni_] = *(const short8*)(bBase + (BUF) * 32768 + ni_ * 2048 + (AXR)); }
#define MM16(R0, AF, BF) { _Pragma("unroll") for (int mi_ = 0; mi_ < 4; ++mi_) { \
    _Pragma("unroll") for (int ni_ = 0; ni_ < 4; ++ni_) \
      acc[(R0) + mi_][ni_] = __builtin_amdgcn_mfma_f32_16x16x32_f16(AF[mi_], BF[ni_], acc[(R0) + mi_][ni_], 0, 0, 0); } }

    f32x4 acc[8][4] = {};

    // prologue: kt0 -> buf0, kt1 -> buf1
    SC_STAGE_A(0, 0, 0); SC_STAGE_A(0, 1, 0); SC_STAGE_B(0, 0, 0); SC_STAGE_B(0, 1, 0);
    SC_STAGE_A(1, 0, 1); SC_STAGE_A(1, 1, 1); SC_STAGE_B(1, 0, 1); SC_STAGE_B(1, 1, 1);
    VMCNT(8);
    SBAR();

#define SC_KT(BUF, PH1STG, PH4STG, VMW) do { \
    short8 aF[4], aG[4], bF[4]; \
    RD_A4(aF, BUF, 0, ax0); RD_B4(bF, BUF, ax0); \
    PH1STG; \
    SBAR(); LGKM0(); PRIO1(); MM16(0, aF, bF); PRIO0(); SBAR(); \
    RD_A4(aG, BUF, 4, ax0); \
    SBAR(); LGKM0(); PRIO1(); MM16(4, aG, bF); PRIO0(); SBAR(); \
    RD_A4(aF, BUF, 0, ax1); RD_B4(bF, BUF, ax1); \
    SBAR(); LGKM0(); PRIO1(); MM16(0, aF, bF); PRIO0(); SBAR(); \
    RD_A4(aG, BUF, 4, ax1); \
    PH4STG; \
    SBAR(); LGKM0(); PRIO1(); MM16(4, aG, bF); PRIO0(); \
    VMW; SBAR(); \
} while (0)

    SC_KT(0, ,
          { SC_STAGE_B(0, 0, 2); SC_STAGE_B(0, 1, 2); },
          VMCNT(4));
    SC_KT(1, { SC_STAGE_A(0, 0, 2); SC_STAGE_A(0, 1, 2); },
          { SC_STAGE_B(1, 0, 3); SC_STAGE_B(1, 1, 3); },
          VMCNT(4));
    SC_KT(0, { SC_STAGE_A(1, 0, 3); SC_STAGE_A(1, 1, 3); },
          ,
          VMCNT(0));
    SC_KT(1, , , );

    // epilogue: per-row top-2 of s = 2*acc - e_sq; 2-step shfl, 4 partials/row/wave
    float4* sRed = (float4*)smem;
    const int cbase = bn + wc * 64 + l15;
    float esq4[4];
    #pragma unroll
    for (int ni = 0; ni < 4; ++ni) esq4[ni] = esqg[cbase + ni * 16];

    #pragma unroll
    for (int mi = 0; mi < 8; ++mi) {
        #pragma unroll
        for (int j = 0; j < 4; ++j) {
            float v1 = -3.4e38f, v2 = -3.4e38f;
            int i1 = 0x7fffffff;
            #pragma unroll
            for (int ni = 0; ni < 4; ++ni) {
                float s = fmaf(2.0f, acc[mi][ni][j], -esq4[ni]);
                int c = cbase + ni * 16;
                if (s > v1) { v2 = v1; v1 = s; i1 = c; }
                else if (s > v2) v2 = s;
            }
            #pragma unroll
            for (int m = 1; m < 4; m <<= 1) {
                float ov1 = __shfl_xor(v1, m, 64);
                int   oi1 = __shfl_xor(i1, m, 64);
                float ov2 = __shfl_xor(v2, m, 64);
                float nv2 = fmaxf(fmaxf(v2, ov2), fminf(v1, ov1));
                if (ov1 > v1 || (ov1 == v1 && oi1 < i1)) { v1 = ov1; i1 = oi1; }
                v2 = nv2;
            }
            if ((l15 & 3) == 0)
                sRed[(((wid << 7) + mi * 16 + rg * 4 + j) << 2) + (l15 >> 2)] =
                    make_float4(v1, __int_as_float(i1), v2, 0.f);
        }
    }
    __syncthreads();
    if (wc < 2) {
        int row = (wc << 6) + lane;
        float v1 = -3.4e38f, v2 = -3.4e38f; int i1 = 0x7fffffff;
        #pragma unroll
        for (int q = 0; q < 4; ++q)
            #pragma unroll
            for (int gq = 0; gq < 4; ++gq) {
                float4 e = sRed[(((((wr << 2) + q) << 7) + row) << 2) + gq];
                float w1 = e.x; int jx = __float_as_int(e.y);
                float nv2 = fmaxf(fmaxf(v2, e.z), fminf(v1, w1));
                if (w1 > v1 || (w1 == v1 && jx < i1)) { v1 = w1; i1 = jx; }
                v2 = nv2;
            }
        int grow = bm + (wr << 7) + row;
        partials[(size_t)grow * 32 + bY] = make_float4(v1, __int_as_float(i1), v2, 0.f);
    }
}

// -------- combine: global top-2 + rigorous rescue decision (gap <= 2*B_r) -----
// B_r = 2*2^-10*||z_r||*maxE (f16 rne cross-terms, inflated) + 0.05 slack.
__global__ __launch_bounds__(256) void combine(const float4* __restrict__ partials,
                                               const float* __restrict__ znorm,
                                               const float* __restrict__ maxe,
                                               int* __restrict__ idx, float* __restrict__ idxf,
                                               float* __restrict__ rescueT) {
    int sub = threadIdx.x & 31;
    int row = blockIdx.x * 8 + (threadIdx.x >> 5);
    float4 p = partials[(size_t)row * 32 + sub];
    float v1 = p.x; int i1 = __float_as_int(p.y); float v2 = p.z;
    #pragma unroll
    for (int m = 1; m < 32; m <<= 1) {
        float ov1 = __shfl_xor(v1, m, 64);
        int   oi1 = __shfl_xor(i1, m, 64);
        float ov2 = __shfl_xor(v2, m, 64);
        float nv2 = fmaxf(fmaxf(v2, ov2), fminf(v1, ov1));
        if (ov1 > v1 || (ov1 == v1 && oi1 < i1)) { v1 = ov1; i1 = oi1; }
        v2 = nv2;
    }
    if (sub == 0) {
        float thr = fmaf(0.0041f * maxe[0], znorm[row], 0.1f);   // 2*B_r
        idx[row] = i1;
        idxf[row] = (float)i1;
        rescueT[row] = (v1 - v2 <= thr) ? (v1 - thr) : 3.0e38f;
    }
}

// ---- exact rescue: read exact zf32 row, rescan candidate tiles in f32 ----
__global__ __launch_bounds__(256) void rescue(const float* __restrict__ zf32,
                                              const float* __restrict__ embed,
                                              const float* __restrict__ esq,
                                              const float4* __restrict__ partials,
                                              const float* __restrict__ rescueT,
                                              int* __restrict__ idx, float* __restrict__ idxf) {
    int row = blockIdx.x;
    float t = rescueT[row];
    if (t > 1.0e38f) return;
    __shared__ __align__(16) float zrow[256];
    __shared__ float sv[256];
    __shared__ int   si[256];
    const int tid = threadIdx.x;
    zrow[tid] = zf32[(size_t)row * 256 + tid];
    __syncthreads();
    float bv = -3.4e38f; int bi = 0x7fffffff;
    for (int nt = 0; nt < 32; ++nt) {
        if (partials[(size_t)row * 32 + nt].x < t) continue;  // block-uniform
        int c = nt * 256 + tid;
        const float4* er = (const float4*)(embed + (size_t)c * 256);
        const float4* zr = (const float4*)zrow;
        float d = 0.f;
        #pragma unroll 4
        for (int k = 0; k < 64; ++k) {
            float4 e4 = er[k], z4 = zr[k];
            d = fmaf(e4.x, z4.x, d); d = fmaf(e4.y, z4.y, d);
            d = fmaf(e4.z, z4.z, d); d = fmaf(e4.w, z4.w, d);
        }
        float s = 2.f * d - esq[c];
        if (s > bv || (s == bv && c < bi)) { bv = s; bi = c; }
    }
    sv[tid] = bv; si[tid] = bi;
    __syncthreads();
    for (int s = 128; s; s >>= 1) {
        if (tid < s) {
            float ov = sv[tid + s]; int oi = si[tid + s];
            if (ov > sv[tid] || (ov == sv[tid] && oi < si[tid])) { sv[tid] = ov; si[tid] = oi; }
        }
        __syncthreads();
    }
    if (tid == 0) { idx[row] = si[0]; idxf[row] = (float)si[0]; }
}

// ====== gemm_out: out = embed[idx]@W_out^T + b_out, 4-term, BM=128 BN=128 =====
__global__ __launch_bounds__(256, 2) void gemm_out_mfma(const short* __restrict__ epk,
                                                        const short* __restrict__ wpk,
                                                        const int* __restrict__ idx,
                                                        const float* __restrict__ b_out,
                                                        float* __restrict__ out) {
    __shared__ __align__(16) char smem[65536];
    const int tid = threadIdx.x;
    const int lane = tid & 63, wid = tid >> 6;
    const int wr = wid >> 1, wc = wid & 1;
    const int l15 = lane & 15, rg = lane >> 4;
    const int bm = blockIdx.x << 7, bn = blockIdx.y << 7;
    const int g = tid & 7, rpb = tid >> 3;

    const char* ebp = (const char*)epk;
    const char* wb = (const char*)wpk;
    const int sw = ((g ^ (rpb & 7)) << 4);
    size_t aoff[4], boff[4];
    #pragma unroll
    for (int it = 0; it < 4; ++it) {
        int c = idx[bm + it * 32 + rpb];
        aoff[it] = (size_t)c * 1024 + sw;
        boff[it] = (size_t)(bn + it * 32 + rpb) * 1024 + sw;
    }

    const int ax0 = ((rg ^ (l15 & 7)) << 4);
    const int ax1 = (((rg + 4) ^ (l15 & 7)) << 4);
    const char* aBase = smem + (wr * 64 + l15) * 128;
    const char* bBase = smem + 16384 + (wc * 64 + l15) * 128;

    f32x4 acc[4][4] = {};

#define GOUT_STAGE(BUF, KT) do { \
    size_t aK = (size_t)((((KT) & 3) | (((KT) >> 3) << 2))) * 128; \
    size_t bK = (size_t)((KT) & 7) * 128; \
    char* dA = smem + (BUF) * 32768 + (tid << 4); \
    char* dB = dA + 16384; \
    _Pragma("unroll") for (int it_ = 0; it_ < 4; ++it_) { \
        GLOAD16(ebp + aoff[it_] + aK, dA + it_ * 4096); \
        GLOAD16(wb + boff[it_] + bK, dB + it_ * 4096); } } while (0)

    GOUT_STAGE(0, 0);
    VMCNT(0);
    __syncthreads();
    #pragma unroll 1
    for (int kt = 0; kt < 16; ++kt) {
        const int buf = kt & 1;
        if (kt + 1 < 16) GOUT_STAGE(buf ^ 1, kt + 1);
        const char* aB = aBase + buf * 32768;
        const char* bB = bBase + buf * 32768;
        #pragma unroll
        for (int ks = 0; ks < 2; ++ks) {
            int ax = ks ? ax1 : ax0;
            short8 aF[4], bF[4];
            #pragma unroll
            for (int mi = 0; mi < 4; ++mi) aF[mi] = *(const short8*)(aB + mi * 2048 + ax);
            #pragma unroll
            for (int ni = 0; ni < 4; ++ni) bF[ni] = *(const short8*)(bB + ni * 2048 + ax);
            #pragma unroll
            for (int mi = 0; mi < 4; ++mi)
                #pragma unroll
                for (int ni = 0; ni < 4; ++ni)
                    acc[mi][ni] = __builtin_amdgcn_mfma_f32_16x16x32_bf16(aF[mi], bF[ni], acc[mi][ni], 0, 0, 0);
        }
        VMCNT(0);
        __syncthreads();
    }
    float bb[4];
    #pragma unroll
    for (int ni = 0; ni < 4; ++ni) bb[ni] = b_out[bn + wc * 64 + ni * 16 + l15];
    #pragma unroll
    for (int mi = 0; mi < 4; ++mi)
        #pragma unroll
        for (int ni = 0; ni < 4; ++ni)
            #pragma unroll
            for (int j = 0; j < 4; ++j) {
                int r = bm + wr * 64 + mi * 16 + rg * 4 + j;
                int c = bn + wc * 64 + ni * 16 + l15;
                out[(size_t)r * 512 + c] = acc[mi][ni][j] + bb[ni];
            }
}

// =================== fallback f32 path (ws too small) =========================
__global__ __launch_bounds__(256) void esq_kernel(const float* __restrict__ embed,
                                                  float* __restrict__ esq) {
    int wave = threadIdx.x >> 6, lane = threadIdx.x & 63;
    int c = (blockIdx.x << 2) + wave;
    float4 v = reinterpret_cast<const float4*>(embed + (size_t)c * CBD)[lane];
    float s = v.x * v.x + v.y * v.y + v.z * v.z + v.w * v.w;
    #pragma unroll
    for (int m = 32; m; m >>= 1) s += __shfl_xor(s, m, 64);
    if (!lane) esq[c] = s;
}

template <bool GATHER>
__global__ __launch_bounds__(256) void gemm_nt(const float* __restrict__ A,
                                               const float* __restrict__ B,
                                               const float* __restrict__ bias,
                                               const int* __restrict__ gather,
                                               float* __restrict__ C,
                                               int M, int N, int K) {
    __shared__ __align__(16) float sA[64][68];
    __shared__ __align__(16) float sB[64][68];
    const int tid = threadIdx.x;
    const int tx = tid & 15, ty = tid >> 4;
    const int bm = blockIdx.x << 6, bn = blockIdx.y << 6;
    float acc[4][4] = {};
    for (int k0 = 0; k0 < K; k0 += 64) {
        #pragma unroll
        for (int i = 0; i < 4; ++i) {
            int f = tid + (i << 8);
            int m = f >> 4;
            int k4 = (f & 15) << 2;
            long arow = bm + m;
            if (GATHER) arow = gather[arow];
            float4 v = *reinterpret_cast<const float4*>(A + arow * K + k0 + k4);
            sA[k4 + 0][m] = v.x; sA[k4 + 1][m] = v.y;
            sA[k4 + 2][m] = v.z; sA[k4 + 3][m] = v.w;
            float4 w = *reinterpret_cast<const float4*>(B + (long)(bn + m) * K + k0 + k4);
            sB[k4 + 0][m] = w.x; sB[k4 + 1][m] = w.y;
            sB[k4 + 2][m] = w.z; sB[k4 + 3][m] = w.w;
        }
        __syncthreads();
        #pragma unroll
        for (int kk = 0; kk < 64; ++kk) {
            float4 a = *reinterpret_cast<const float4*>(&sA[kk][ty << 2]);
            float4 b = *reinterpret_cast<const float4*>(&sB[kk][tx << 2]);
            float av[4] = {a.x, a.y, a.z, a.w};
            float bv[4] = {b.x, b.y, b.z, b.w};
            #pragma unroll
            for (int i = 0; i < 4; ++i)
                #pragma unroll
                for (int j = 0; j < 4; ++j)
                    acc[i][j] = fmaf(av[i], bv[j], acc[i][j]);
        }
        __syncthreads();
    }
    #pragma unroll
    for (int i = 0; i < 4; ++i) {
        long m = bm + (ty << 2) + i;
        #pragma unroll
        for (int j = 0; j < 4; ++j) {
            int n = bn + (tx << 2) + j;
            C[m * N + n] = acc[i][j] + bias[n];
        }
    }
}

__global__ __launch_bounds__(256) void score_argmax(const float* __restrict__ z,
                                                    const float* __restrict__ embed,
                                                    const float* __restrict__ esq,
                                                    int* __restrict__ idx_out,
                                                    float* __restrict__ idx_f32) {
    __shared__ __align__(16) float sZ[64][68];
    __shared__ __align__(16) float sE[64][68];
    const int tid = threadIdx.x;
    const int tx = tid & 15, ty = tid >> 4;
    const int bm = blockIdx.x << 6;
    float best[4];
    int bidx[4];
    #pragma unroll
    for (int i = 0; i < 4; ++i) { best[i] = -3.4e38f; bidx[i] = 0; }
    for (int ct = 0; ct < CBS; ct += 64) {
        float acc[4][4] = {};
        for (int k0 = 0; k0 < CBD; k0 += 64) {
            #pragma unroll
            for (int i = 0; i < 4; ++i) {
                int f = tid + (i << 8);
                int m = f >> 4;
                int k4 = (f & 15) << 2;
                float4 v = *reinterpret_cast<const float4*>(z + (long)(bm + m) * CBD + k0 + k4);
                sZ[k4 + 0][m] = v.x; sZ[k4 + 1][m] = v.y;
                sZ[k4 + 2][m] = v.z; sZ[k4 + 3][m] = v.w;
                float4 w = *reinterpret_cast<const float4*>(embed + (long)(ct + m) * CBD + k0 + k4);
                sE[k4 + 0][m] = w.x; sE[k4 + 1][m] = w.y;
                sE[k4 + 2][m] = w.z; sE[k4 + 3][m] = w.w;
            }
            __syncthreads();
            #pragma unroll
            for (int kk = 0; kk < 64; ++kk) {
                float4 a = *reinterpret_cast<const float4*>(&sZ[kk][ty << 2]);
                float4 b = *reinterpret_cast<const float4*>(&sE[kk][tx << 2]);
                float av[4] = {a.x, a.y, a.z, a.w};
                float bv[4] = {b.x, b.y, b.z, b.w};
                #pragma unroll
                for (int i = 0; i < 4; ++i)
                    #pragma unroll
                    for (int j = 0; j < 4; ++j)
                        acc[i][j] = fmaf(av[i], bv[j], acc[i][j]);
            }
            __syncthreads();
        }
        #pragma unroll
        for (int j = 0; j < 4; ++j) {
            int c = ct + (tx << 2) + j;
            float eq = esq[c];
            #pragma unroll
            for (int i = 0; i < 4; ++i) {
                float s = 2.0f * acc[i][j] - eq;
                if (s > best[i] || (s == best[i] && c < bidx[i])) { best[i] = s; bidx[i] = c; }
            }
        }
    }
    #pragma unroll
    for (int i = 0; i < 4; ++i) {
        float b = best[i];
        int bi = bidx[i];
        #pragma unroll
        for (int m = 1; m < 16; m <<= 1) {
            float ob = __shfl_xor(b, m, 64);
            int oi = __shfl_xor(bi, m, 64);
            if (ob > b || (ob == b && oi < bi)) { b = ob; bi = oi; }
        }
        if (tx == 0) {
            int row = bm + (ty << 2) + i;
            idx_out[row] = bi;
            idx_f32[row] = (float)bi;
        }
    }
}

extern "C" void kernel_launch(void* const* d_in, const int* in_sizes, int n_in,
                              void* d_out, int out_size, void* d_ws, size_t ws_size,
                              hipStream_t stream) {
    const float* x     = (const float*)d_in[0];
    const float* embed = (const float*)d_in[1];
    const float* W_in  = (const float*)d_in[2];
    const float* b_in  = (const float*)d_in[3];
    const float* W_out = (const float*)d_in[4];
    const float* b_out = (const float*)d_in[5];

    float* out_idx = (float*)d_out;              // [16384] indices as float
    float* out     = (float*)d_out + N_TOK;      // [16384,512]

    // workspace layout (main path). partials aliases xpack (dead after gemm_in).
    char* ws = (char*)d_ws;
    float*  esq      = (float*)ws;                                   // 32KB
    float*  rescueT  = (float*)(ws + 32768);                         // 64KB
    int*    idx      = (int*)(ws + 98304);                           // 64KB
    float*  znorm    = (float*)(ws + 163840);                        // 64KB
    float*  maxe     = (float*)(ws + 229376);                        // 256B
    short*  xpack    = (short*)(ws + 229632);                        // 33.55MB
    float4* partials = (float4*)(ws + 229632);                       // 8MB (alias)
    float*  zf32     = (float*)(ws + 229632 + 33554432);             // 16.78MB
    short*  z16      = (short*)((char*)zf32 + 16777216);             // 8.39MB
    short*  e16      = z16 + (size_t)N_TOK * 256;                    // 4.19MB
    short*  epack    = e16 + (size_t)CBS * 256;                      // 8.39MB
    short*  winpk    = epack + (size_t)CBS * 512;                    // 0.52MB
    short*  wopk     = winpk + (size_t)CBD * 1024;                   // 0.52MB
    size_t need = (size_t)((char*)(wopk + (size_t)DIM * 512) - ws);

    if (ws_size >= need) {
        pack_w<9><<<(N_TOK * DIM) / 256, 256, 0, stream>>>(x, xpack);
        pack_w<9><<<(CBD * DIM) / 256, 256, 0, stream>>>(W_in, winpk);
        pack_w<8><<<(DIM * CBD) / 256, 256, 0, stream>>>(W_out, wopk);
        prep_embed<<<CBS / 4, 256, 0, stream>>>(embed, esq, epack, e16);
        maxe_k<<<1, 256, 0, stream>>>(esq, maxe);
        // z = x@W_in^T + b_in (4-term MFMA) -> z16 (f16) + zf32 (exact)
        gemm_in_mfma<<<dim3(N_TOK / 64, 2), 256, 0, stream>>>(xpack, winpk, b_in, z16, zf32);
        znorm_k<<<N_TOK / 4, 256, 0, stream>>>(zf32, znorm);
        // fp16 1-term scores + per-tile top-2
        score_mfma<<<2048, 512, 0, stream>>>(z16, e16, esq, partials);
        // combine -> idx + f16-bound rescue thresholds
        combine<<<N_TOK / 8, 256, 0, stream>>>(partials, znorm, maxe, idx, out_idx, rescueT);
        // exact rescue (zf32-based; scans only candidate tiles)
        rescue<<<N_TOK, 256, 0, stream>>>(zf32, embed, esq, partials, rescueT, idx, out_idx);
        // out = embed[idx]@W_out^T + b_out
        gemm_out_mfma<<<dim3(N_TOK / 128, 4), 256, 0, stream>>>(epack, wopk, idx, b_out, out);
    } else {
        float* z   = (float*)d_ws;
        float* es  = z + (size_t)N_TOK * CBD;
        int*   id  = (int*)(es + CBS);
        gemm_nt<false><<<dim3(N_TOK / 64, CBD / 64), 256, 0, stream>>>(
            x, W_in, b_in, nullptr, z, N_TOK, CBD, DIM);
        esq_kernel<<<CBS / 4, 256, 0, stream>>>(embed, es);
        score_argmax<<<N_TOK / 64, 256, 0, stream>>>(z, embed, es, id, out_idx);
        gemm_nt<true><<<dim3(N_TOK / 64, DIM / 64), 256, 0, stream>>>(
            embed, W_out, b_out, id, out, N_TOK, DIM, CBD);
    }
}

// Round 9
// 304.684 us; speedup vs baseline: 4.2315x; 1.5257x over previous
//
#include <hip/hip_runtime.h>

#define N_TOK 16384   // B*T = 8*2048
#define DIM   512
#define CBD   256     // codebook dim
#define CBS   8192    // codebook size

typedef short short8 __attribute__((ext_vector_type(8)));
typedef float f32x4 __attribute__((ext_vector_type(4)));

#define GLOAD16(g, l) __builtin_amdgcn_global_load_lds( \
    (const __attribute__((address_space(1))) void*)(g), \
    (__attribute__((address_space(3))) void*)(l), 16, 0, 0)

#define SBAR() do { asm volatile("" ::: "memory"); \
                    __builtin_amdgcn_s_barrier();  \
                    asm volatile("" ::: "memory"); } while (0)
#define LGKM0() asm volatile("s_waitcnt lgkmcnt(0)" ::: "memory")
#define VMCNT(n) asm volatile("s_waitcnt vmcnt(" #n ")" ::: "memory")
#define PRIO1() __builtin_amdgcn_s_setprio(1)
#define PRIO0() __builtin_amdgcn_s_setprio(0)

__device__ inline unsigned short f2bf_rne(float f) {
    unsigned u = __float_as_uint(f);
    unsigned r = (u + 0x7FFFu + ((u >> 16) & 1u)) >> 16;
    return (unsigned short)r;
}
__device__ inline float bf2f(unsigned short h) { return __uint_as_float((unsigned)h << 16); }
__device__ inline short f2h(float f) {
    _Float16 h = (_Float16)f;           // v_cvt_f16_f32, RNE
    short r; __builtin_memcpy(&r, &h, 2); return r;
}
__device__ inline float h2f(short s) {
    _Float16 h; __builtin_memcpy(&h, &s, 2); return (float)h;
}

// ================= packing: 2-term split [hi(K) | lo(K)] per row ==============
template <int LOGK>
__global__ __launch_bounds__(256) void pack_w(const float* __restrict__ src, short* __restrict__ dst) {
    int e = blockIdx.x * 256 + threadIdx.x;
    int r = e >> LOGK, k = e & ((1 << LOGK) - 1);
    float v = src[e];
    unsigned short h = f2bf_rne(v);
    unsigned short l = f2bf_rne(v - bf2f(h));
    size_t base = (size_t)r << (LOGK + 1);
    dst[base + k] = (short)h;
    dst[base + (1 << LOGK) + k] = (short)l;
}

// fused: e_sq + 2-term bf16 pack (gemm_out) + f16 pack (score) + ||e-e16||^2
__global__ __launch_bounds__(256) void prep_embed(const float* __restrict__ embed,
                                                  float* __restrict__ esq,
                                                  short* __restrict__ epack,
                                                  short* __restrict__ e16,
                                                  float* __restrict__ denorm) {
    int wave = threadIdx.x >> 6, lane = threadIdx.x & 63;
    int c = (blockIdx.x << 2) + wave;
    float4 v = reinterpret_cast<const float4*>(embed + (size_t)c * CBD)[lane];
    short4 hs, ls, fs;
    {
        unsigned short h, l;
        h = f2bf_rne(v.x); l = f2bf_rne(v.x - bf2f(h)); hs.x = h; ls.x = l;
        h = f2bf_rne(v.y); l = f2bf_rne(v.y - bf2f(h)); hs.y = h; ls.y = l;
        h = f2bf_rne(v.z); l = f2bf_rne(v.z - bf2f(h)); hs.z = h; ls.z = l;
        h = f2bf_rne(v.w); l = f2bf_rne(v.w - bf2f(h)); hs.w = h; ls.w = l;
    }
    fs.x = f2h(v.x); fs.y = f2h(v.y); fs.z = f2h(v.z); fs.w = f2h(v.w);
    reinterpret_cast<short4*>(epack + (size_t)c * 512)[lane] = hs;
    reinterpret_cast<short4*>(epack + (size_t)c * 512 + 256)[lane] = ls;
    reinterpret_cast<short4*>(e16 + (size_t)c * 256)[lane] = fs;
    float s = v.x * v.x + v.y * v.y + v.z * v.z + v.w * v.w;
    float dx = v.x - h2f(fs.x), dy = v.y - h2f(fs.y);
    float dz = v.z - h2f(fs.z), dw = v.w - h2f(fs.w);
    float ds = dx * dx + dy * dy + dz * dz + dw * dw;
    #pragma unroll
    for (int m = 32; m; m >>= 1) { s += __shfl_xor(s, m, 64); ds += __shfl_xor(ds, m, 64); }
    if (!lane) { esq[c] = s; denorm[c] = ds; }
}

// ---- znorm2[r] = (||z16||, ||zf32 - z16||) ----
__global__ __launch_bounds__(256) void znorm_k(const float* __restrict__ zf32,
                                               const short* __restrict__ z16,
                                               float2* __restrict__ znorm2) {
    int wave = threadIdx.x >> 6, lane = threadIdx.x & 63;
    int r = blockIdx.x * 4 + wave;
    float4 v = reinterpret_cast<const float4*>(zf32 + (size_t)r * 256)[lane];
    short4 h = reinterpret_cast<const short4*>(z16 + (size_t)r * 256)[lane];
    float a = h2f(h.x), b = h2f(h.y), c = h2f(h.z), d = h2f(h.w);
    float s16 = a * a + b * b + c * c + d * d;
    float dx = v.x - a, dy = v.y - b, dz = v.z - c, dw = v.w - d;
    float ds = dx * dx + dy * dy + dz * dz + dw * dw;
    #pragma unroll
    for (int m = 32; m; m >>= 1) { s16 += __shfl_xor(s16, m, 64); ds += __shfl_xor(ds, m, 64); }
    if (!lane) znorm2[r] = make_float2(sqrtf(s16), sqrtf(ds));
}

// ---- maxe[0] = max_c ||e_c||, maxe[1] = max_c ||e_c - e16_c|| ----
__global__ __launch_bounds__(256) void maxe_k(const float* __restrict__ esq,
                                              const float* __restrict__ denorm,
                                              float* __restrict__ maxe) {
    float m = 0.f, md = 0.f;
    #pragma unroll
    for (int k = 0; k < 32; ++k) {
        m = fmaxf(m, esq[threadIdx.x + (k << 8)]);
        md = fmaxf(md, denorm[threadIdx.x + (k << 8)]);
    }
    #pragma unroll
    for (int s = 32; s; s >>= 1) {
        m = fmaxf(m, __shfl_xor(m, s, 64));
        md = fmaxf(md, __shfl_xor(md, s, 64));
    }
    __shared__ float w[4], wd[4];
    if (!(threadIdx.x & 63)) { w[threadIdx.x >> 6] = m; wd[threadIdx.x >> 6] = md; }
    __syncthreads();
    if (threadIdx.x == 0) {
        maxe[0] = sqrtf(fmaxf(fmaxf(w[0], w[1]), fmaxf(w[2], w[3])));
        maxe[1] = sqrtf(fmaxf(fmaxf(wd[0], wd[1]), fmaxf(wd[2], wd[3])));
    }
}

// ============ gemm_in: z = x@W_in^T + b_in, 4-term split-bf16, BM=64 BN=128 ===
// Writes z16 (f16, for score) and zf32 (exact f32, for rescue).
__global__ __launch_bounds__(256, 3) void gemm_in_mfma(const short* __restrict__ xpk,
                                                       const short* __restrict__ wpk,
                                                       const float* __restrict__ b_in,
                                                       short* __restrict__ z16,
                                                       float* __restrict__ zf32) {
    __shared__ __align__(16) char smem[49152];
    const int tid = threadIdx.x;
    const int lane = tid & 63, wid = tid >> 6;
    const int l15 = lane & 15, rg = lane >> 4;
    const int bm = blockIdx.x << 6, bn = blockIdx.y << 7;
    const int g = tid & 7, rpb = tid >> 3;

    const char* xb = (const char*)xpk;
    const char* wb = (const char*)wpk;
    const int sw = ((g ^ (rpb & 7)) << 4);
    size_t aoff[2], boff[2][2];
    #pragma unroll
    for (int it = 0; it < 2; ++it)
        aoff[it] = (size_t)(bm + it * 32 + rpb) * 2048 + sw;
    #pragma unroll
    for (int it = 0; it < 4; ++it)
        boff[it >> 1][it & 1] = (size_t)(bn + it * 32 + rpb) * 2048 + sw;

    const int ax0 = ((rg ^ (l15 & 7)) << 4);
    const int ax1 = (((rg + 4) ^ (l15 & 7)) << 4);
    const char* aBase = smem + l15 * 128;
    const char* bBase = smem + 8192 + (wid * 32 + l15) * 128;

    f32x4 acc[4][2] = {};

#define GIN_STAGE(BUF, KT) do { \
    size_t aK = (size_t)(((((KT) >> 4) << 3) | ((KT) & 7))) * 128; \
    size_t bK = (size_t)((((((KT) >> 3) & 1) << 3) | ((KT) & 7))) * 128; \
    char* dA = smem + (BUF) * 24576 + (tid << 4); \
    char* dB = dA + 8192; \
    GLOAD16(xb + aoff[0] + aK, dA); \
    GLOAD16(xb + aoff[1] + aK, dA + 4096); \
    GLOAD16(wb + boff[0][0] + bK, dB); \
    GLOAD16(wb + boff[0][1] + bK, dB + 4096); \
    GLOAD16(wb + boff[1][0] + bK, dB + 8192); \
    GLOAD16(wb + boff[1][1] + bK, dB + 12288); } while (0)

    GIN_STAGE(0, 0);
    VMCNT(0);
    __syncthreads();
    #pragma unroll 1
    for (int kt = 0; kt < 32; ++kt) {
        const int buf = kt & 1;
        if (kt + 1 < 32) GIN_STAGE(buf ^ 1, kt + 1);
        const char* aB = aBase + buf * 24576;
        const char* bB = bBase + buf * 24576;
        #pragma unroll
        for (int ks = 0; ks < 2; ++ks) {
            int ax = ks ? ax1 : ax0;
            short8 aF[4], bF[2];
            #pragma unroll
            for (int mi = 0; mi < 4; ++mi) aF[mi] = *(const short8*)(aB + mi * 2048 + ax);
            #pragma unroll
            for (int ni = 0; ni < 2; ++ni) bF[ni] = *(const short8*)(bB + ni * 2048 + ax);
            #pragma unroll
            for (int mi = 0; mi < 4; ++mi)
                #pragma unroll
                for (int ni = 0; ni < 2; ++ni)
                    acc[mi][ni] = __builtin_amdgcn_mfma_f32_16x16x32_bf16(aF[mi], bF[ni], acc[mi][ni], 0, 0, 0);
        }
        VMCNT(0);
        __syncthreads();
    }
    float bb[2];
    #pragma unroll
    for (int ni = 0; ni < 2; ++ni) bb[ni] = b_in[bn + wid * 32 + ni * 16 + l15];
    #pragma unroll
    for (int mi = 0; mi < 4; ++mi)
        #pragma unroll
        for (int ni = 0; ni < 2; ++ni)
            #pragma unroll
            for (int j = 0; j < 4; ++j) {
                int r = bm + mi * 16 + rg * 4 + j;
                int c = bn + wid * 32 + ni * 16 + l15;
                float s = acc[mi][ni][j] + bb[ni];
                z16[(size_t)r * 256 + c] = f2h(s);
                zf32[(size_t)r * 256 + c] = s;
            }
}

// ===== score: 256x256, K=256 (4 kt of 64), 1-term FP16 (z16·e16), top-2 epilogue
__global__ __launch_bounds__(512, 2) void score_mfma(const short* __restrict__ zpk,
                                                     const short* __restrict__ epk,
                                                     const float* __restrict__ esqg,
                                                     float4* __restrict__ partials) {
    __shared__ __align__(16) char smem[131072];
    const int tid = threadIdx.x;
    const int lane = tid & 63, wid = tid >> 6;
    const int wr = wid >> 2, wc = wid & 3;
    const int l15 = lane & 15, rg = lane >> 4;

    int flat = blockIdx.x;
    int xcd = flat & 7, ix = flat >> 3;
    int bX = xcd * 8 + (ix & 7), bY = ix >> 3;
    const int bm = bX << 8, bn = bY << 8;
    const size_t bmB = (size_t)bX << 17;         // rows*512B
    const size_t bnB = (size_t)bY << 17;

    const char* zb = (const char*)zpk;
    const char* eb = (const char*)epk;
    const int g = tid & 7, rp0 = tid >> 3;       // rp0 0..63
    const size_t arow = (size_t)rp0 * 512 + ((g ^ (rp0 & 7)) << 4);

#define SC_STAGE_A(BUF, H, KT) do { \
    const char* s_ = zb + bmB + (size_t)(H) * 65536 + (size_t)(KT) * 128 + arow; \
    char* d_ = smem + (BUF) * 32768 + (H) * 16384 + (tid << 4); \
    GLOAD16(s_, d_); GLOAD16(s_ + 32768, d_ + 8192); } while (0)
#define SC_STAGE_B(BUF, H, KT) do { \
    const char* s_ = eb + bnB + (size_t)(H) * 65536 + (size_t)(KT) * 128 + arow; \
    char* d_ = smem + 65536 + (BUF) * 32768 + (H) * 16384 + (tid << 4); \
    GLOAD16(s_, d_); GLOAD16(s_ + 32768, d_ + 8192); } while (0)

    const int ax0 = ((rg ^ (l15 & 7)) << 4);
    const int ax1 = (((rg + 4) ^ (l15 & 7)) << 4);
    const char* aBase = smem + wr * 16384 + l15 * 128;
    const char* bBase = smem + 65536 + (wc >> 1) * 16384 + ((wc & 1) * 64 + l15) * 128;

#define RD_A4(DST, BUF, MIB, AXR) { _Pragma("unroll") for (int mi_ = 0; mi_ < 4; ++mi_) \
    DST[mi_] = *(const short8*)(aBase + (BUF) * 32768 + ((MIB) + mi_) * 2048 + (AXR)); }
#define RD_B4(DST, BUF, AXR) { _Pragma("unroll") for (int ni_ = 0; ni_ < 4; ++ni_) \
    DST[ni_] = *(const short8*)(bBase + (BUF) * 32768 + ni_ * 2048 + (AXR)); }
#define MM16(R0, AF, BF) { _Pragma("unroll") for (int mi_ = 0; mi_ < 4; ++mi_) { \
    _Pragma("unroll") for (int ni_ = 0; ni_ < 4; ++ni_) \
      acc[(R0) + mi_][ni_] = __builtin_amdgcn_mfma_f32_16x16x32_f16(AF[mi_], BF[ni_], acc[(R0) + mi_][ni_], 0, 0, 0); } }

    f32x4 acc[8][4] = {};

    // prologue: kt0 -> buf0, kt1 -> buf1
    SC_STAGE_A(0, 0, 0); SC_STAGE_A(0, 1, 0); SC_STAGE_B(0, 0, 0); SC_STAGE_B(0, 1, 0);
    SC_STAGE_A(1, 0, 1); SC_STAGE_A(1, 1, 1); SC_STAGE_B(1, 0, 1); SC_STAGE_B(1, 1, 1);
    VMCNT(8);
    SBAR();

#define SC_KT(BUF, PH1STG, PH4STG, VMW) do { \
    short8 aF[4], aG[4], bF[4]; \
    RD_A4(aF, BUF, 0, ax0); RD_B4(bF, BUF, ax0); \
    PH1STG; \
    SBAR(); LGKM0(); PRIO1(); MM16(0, aF, bF); PRIO0(); SBAR(); \
    RD_A4(aG, BUF, 4, ax0); \
    SBAR(); LGKM0(); PRIO1(); MM16(4, aG, bF); PRIO0(); SBAR(); \
    RD_A4(aF, BUF, 0, ax1); RD_B4(bF, BUF, ax1); \
    SBAR(); LGKM0(); PRIO1(); MM16(0, aF, bF); PRIO0(); SBAR(); \
    RD_A4(aG, BUF, 4, ax1); \
    PH4STG; \
    SBAR(); LGKM0(); PRIO1(); MM16(4, aG, bF); PRIO0(); \
    VMW; SBAR(); \
} while (0)

    SC_KT(0, ,
          { SC_STAGE_B(0, 0, 2); SC_STAGE_B(0, 1, 2); },
          VMCNT(4));
    SC_KT(1, { SC_STAGE_A(0, 0, 2); SC_STAGE_A(0, 1, 2); },
          { SC_STAGE_B(1, 0, 3); SC_STAGE_B(1, 1, 3); },
          VMCNT(4));
    SC_KT(0, { SC_STAGE_A(1, 0, 3); SC_STAGE_A(1, 1, 3); },
          ,
          VMCNT(0));
    SC_KT(1, , , );

    // epilogue: per-row top-2 of s = 2*acc - e_sq; 2-step shfl, 4 partials/row/wave
    float4* sRed = (float4*)smem;
    const int cbase = bn + wc * 64 + l15;
    float esq4[4];
    #pragma unroll
    for (int ni = 0; ni < 4; ++ni) esq4[ni] = esqg[cbase + ni * 16];

    #pragma unroll
    for (int mi = 0; mi < 8; ++mi) {
        #pragma unroll
        for (int j = 0; j < 4; ++j) {
            float v1 = -3.4e38f, v2 = -3.4e38f;
            int i1 = 0x7fffffff;
            #pragma unroll
            for (int ni = 0; ni < 4; ++ni) {
                float s = fmaf(2.0f, acc[mi][ni][j], -esq4[ni]);
                int c = cbase + ni * 16;
                if (s > v1) { v2 = v1; v1 = s; i1 = c; }
                else if (s > v2) v2 = s;
            }
            #pragma unroll
            for (int m = 1; m < 4; m <<= 1) {
                float ov1 = __shfl_xor(v1, m, 64);
                int   oi1 = __shfl_xor(i1, m, 64);
                float ov2 = __shfl_xor(v2, m, 64);
                float nv2 = fmaxf(fmaxf(v2, ov2), fminf(v1, ov1));
                if (ov1 > v1 || (ov1 == v1 && oi1 < i1)) { v1 = ov1; i1 = oi1; }
                v2 = nv2;
            }
            if ((l15 & 3) == 0)
                sRed[(((wid << 7) + mi * 16 + rg * 4 + j) << 2) + (l15 >> 2)] =
                    make_float4(v1, __int_as_float(i1), v2, 0.f);
        }
    }
    __syncthreads();
    if (wc < 2) {
        int row = (wc << 6) + lane;
        float v1 = -3.4e38f, v2 = -3.4e38f; int i1 = 0x7fffffff;
        #pragma unroll
        for (int q = 0; q < 4; ++q)
            #pragma unroll
            for (int gq = 0; gq < 4; ++gq) {
                float4 e = sRed[(((((wr << 2) + q) << 7) + row) << 2) + gq];
                float w1 = e.x; int jx = __float_as_int(e.y);
                float nv2 = fmaxf(fmaxf(v2, e.z), fminf(v1, w1));
                if (w1 > v1 || (w1 == v1 && jx < i1)) { v1 = w1; i1 = jx; }
                v2 = nv2;
            }
        int grow = bm + (wr << 7) + row;
        partials[(size_t)grow * 32 + bY] = make_float4(v1, __int_as_float(i1), v2, 0.f);
    }
}

// -------- combine: global top-2 + measured-norm rescue decision ---------------
// |s~ - s| <= B_r = 2*(||dz||*maxE + ||z16||*maxDe); thr = 2.1*(...) + 0.02.
__global__ __launch_bounds__(256) void combine(const float4* __restrict__ partials,
                                               const float2* __restrict__ znorm2,
                                               const float* __restrict__ maxe,
                                               int* __restrict__ idx, float* __restrict__ idxf,
                                               float* __restrict__ rescueT) {
    int sub = threadIdx.x & 31;
    int row = blockIdx.x * 8 + (threadIdx.x >> 5);
    float4 p = partials[(size_t)row * 32 + sub];
    float v1 = p.x; int i1 = __float_as_int(p.y); float v2 = p.z;
    #pragma unroll
    for (int m = 1; m < 32; m <<= 1) {
        float ov1 = __shfl_xor(v1, m, 64);
        int   oi1 = __shfl_xor(i1, m, 64);
        float ov2 = __shfl_xor(v2, m, 64);
        float nv2 = fmaxf(fmaxf(v2, ov2), fminf(v1, ov1));
        if (ov1 > v1 || (ov1 == v1 && oi1 < i1)) { v1 = ov1; i1 = oi1; }
        v2 = nv2;
    }
    if (sub == 0) {
        float2 zn = znorm2[row];
        float thr = fmaf(2.1f, zn.y * maxe[0] + zn.x * maxe[1], 0.02f);
        idx[row] = i1;
        idxf[row] = (float)i1;
        rescueT[row] = (v1 - v2 <= thr) ? (v1 - thr) : 3.0e38f;
    }
}

// ---- exact rescue: 16 lanes per code (coalesced 256B segments), f32 rescan ----
__global__ __launch_bounds__(256) void rescue(const float* __restrict__ zf32,
                                              const float* __restrict__ embed,
                                              const float* __restrict__ esq,
                                              const float4* __restrict__ partials,
                                              const float* __restrict__ rescueT,
                                              int* __restrict__ idx, float* __restrict__ idxf) {
    int row = blockIdx.x;
    float t = rescueT[row];
    if (t > 1.0e38f) return;
    __shared__ __align__(16) float zrow[256];
    __shared__ float gv[16];
    __shared__ int   gi[16];
    const int tid = threadIdx.x;
    const int grp = tid >> 4, ln = tid & 15;
    zrow[tid] = zf32[(size_t)row * 256 + tid];
    __syncthreads();
    const float4* zr = (const float4*)zrow;
    float bv = -3.4e38f; int bi = 0x7fffffff;
    for (int nt = 0; nt < 32; ++nt) {
        if (partials[(size_t)row * 32 + nt].x < t) continue;  // block-uniform
        #pragma unroll 1
        for (int it = 0; it < 16; ++it) {
            int c = nt * 256 + it * 16 + grp;
            const float4* er = (const float4*)(embed + (size_t)c * 256);
            float d = 0.f;
            #pragma unroll
            for (int q = 0; q < 4; ++q) {
                float4 e4 = er[q * 16 + ln];
                float4 z4 = zr[q * 16 + ln];
                d = fmaf(e4.x, z4.x, d); d = fmaf(e4.y, z4.y, d);
                d = fmaf(e4.z, z4.z, d); d = fmaf(e4.w, z4.w, d);
            }
            #pragma unroll
            for (int m = 1; m < 16; m <<= 1) d += __shfl_xor(d, m, 64);
            if (ln == 0) {
                float s = 2.f * d - esq[c];
                if (s > bv || (s == bv && c < bi)) { bv = s; bi = c; }
            }
        }
    }
    if (ln == 0) { gv[grp] = bv; gi[grp] = bi; }
    __syncthreads();
    if (tid == 0) {
        float v = gv[0]; int i = gi[0];
        #pragma unroll
        for (int k = 1; k < 16; ++k)
            if (gv[k] > v || (gv[k] == v && gi[k] < i)) { v = gv[k]; i = gi[k]; }
        idx[row] = i; idxf[row] = (float)i;
    }
}

// ====== gemm_out: out = embed[idx]@W_out^T + b_out, 4-term, BM=128 BN=128 =====
__global__ __launch_bounds__(256, 2) void gemm_out_mfma(const short* __restrict__ epk,
                                                        const short* __restrict__ wpk,
                                                        const int* __restrict__ idx,
                                                        const float* __restrict__ b_out,
                                                        float* __restrict__ out) {
    __shared__ __align__(16) char smem[65536];
    const int tid = threadIdx.x;
    const int lane = tid & 63, wid = tid >> 6;
    const int wr = wid >> 1, wc = wid & 1;
    const int l15 = lane & 15, rg = lane >> 4;
    const int bm = blockIdx.x << 7, bn = blockIdx.y << 7;
    const int g = tid & 7, rpb = tid >> 3;

    const char* ebp = (const char*)epk;
    const char* wb = (const char*)wpk;
    const int sw = ((g ^ (rpb & 7)) << 4);
    size_t aoff[4], boff[4];
    #pragma unroll
    for (int it = 0; it < 4; ++it) {
        int c = idx[bm + it * 32 + rpb];
        aoff[it] = (size_t)c * 1024 + sw;
        boff[it] = (size_t)(bn + it * 32 + rpb) * 1024 + sw;
    }

    const int ax0 = ((rg ^ (l15 & 7)) << 4);
    const int ax1 = (((rg + 4) ^ (l15 & 7)) << 4);
    const char* aBase = smem + (wr * 64 + l15) * 128;
    const char* bBase = smem + 16384 + (wc * 64 + l15) * 128;

    f32x4 acc[4][4] = {};

#define GOUT_STAGE(BUF, KT) do { \
    size_t aK = (size_t)((((KT) & 3) | (((KT) >> 3) << 2))) * 128; \
    size_t bK = (size_t)((KT) & 7) * 128; \
    char* dA = smem + (BUF) * 32768 + (tid << 4); \
    char* dB = dA + 16384; \
    _Pragma("unroll") for (int it_ = 0; it_ < 4; ++it_) { \
        GLOAD16(ebp + aoff[it_] + aK, dA + it_ * 4096); \
        GLOAD16(wb + boff[it_] + bK, dB + it_ * 4096); } } while (0)

    GOUT_STAGE(0, 0);
    VMCNT(0);
    __syncthreads();
    #pragma unroll 1
    for (int kt = 0; kt < 16; ++kt) {
        const int buf = kt & 1;
        if (kt + 1 < 16) GOUT_STAGE(buf ^ 1, kt + 1);
        const char* aB = aBase + buf * 32768;
        const char* bB = bBase + buf * 32768;
        #pragma unroll
        for (int ks = 0; ks < 2; ++ks) {
            int ax = ks ? ax1 : ax0;
            short8 aF[4], bF[4];
            #pragma unroll
            for (int mi = 0; mi < 4; ++mi) aF[mi] = *(const short8*)(aB + mi * 2048 + ax);
            #pragma unroll
            for (int ni = 0; ni < 4; ++ni) bF[ni] = *(const short8*)(bB + ni * 2048 + ax);
            #pragma unroll
            for (int mi = 0; mi < 4; ++mi)
                #pragma unroll
                for (int ni = 0; ni < 4; ++ni)
                    acc[mi][ni] = __builtin_amdgcn_mfma_f32_16x16x32_bf16(aF[mi], bF[ni], acc[mi][ni], 0, 0, 0);
        }
        VMCNT(0);
        __syncthreads();
    }
    float bb[4];
    #pragma unroll
    for (int ni = 0; ni < 4; ++ni) bb[ni] = b_out[bn + wc * 64 + ni * 16 + l15];
    #pragma unroll
    for (int mi = 0; mi < 4; ++mi)
        #pragma unroll
        for (int ni = 0; ni < 4; ++ni)
            #pragma unroll
            for (int j = 0; j < 4; ++j) {
                int r = bm + wr * 64 + mi * 16 + rg * 4 + j;
                int c = bn + wc * 64 + ni * 16 + l15;
                out[(size_t)r * 512 + c] = acc[mi][ni][j] + bb[ni];
            }
}

// =================== fallback f32 path (ws too small) =========================
__global__ __launch_bounds__(256) void esq_kernel(const float* __restrict__ embed,
                                                  float* __restrict__ esq) {
    int wave = threadIdx.x >> 6, lane = threadIdx.x & 63;
    int c = (blockIdx.x << 2) + wave;
    float4 v = reinterpret_cast<const float4*>(embed + (size_t)c * CBD)[lane];
    float s = v.x * v.x + v.y * v.y + v.z * v.z + v.w * v.w;
    #pragma unroll
    for (int m = 32; m; m >>= 1) s += __shfl_xor(s, m, 64);
    if (!lane) esq[c] = s;
}

template <bool GATHER>
__global__ __launch_bounds__(256) void gemm_nt(const float* __restrict__ A,
                                               const float* __restrict__ B,
                                               const float* __restrict__ bias,
                                               const int* __restrict__ gather,
                                               float* __restrict__ C,
                                               int M, int N, int K) {
    __shared__ __align__(16) float sA[64][68];
    __shared__ __align__(16) float sB[64][68];
    const int tid = threadIdx.x;
    const int tx = tid & 15, ty = tid >> 4;
    const int bm = blockIdx.x << 6, bn = blockIdx.y << 6;
    float acc[4][4] = {};
    for (int k0 = 0; k0 < K; k0 += 64) {
        #pragma unroll
        for (int i = 0; i < 4; ++i) {
            int f = tid + (i << 8);
            int m = f >> 4;
            int k4 = (f & 15) << 2;
            long arow = bm + m;
            if (GATHER) arow = gather[arow];
            float4 v = *reinterpret_cast<const float4*>(A + arow * K + k0 + k4);
            sA[k4 + 0][m] = v.x; sA[k4 + 1][m] = v.y;
            sA[k4 + 2][m] = v.z; sA[k4 + 3][m] = v.w;
            float4 w = *reinterpret_cast<const float4*>(B + (long)(bn + m) * K + k0 + k4);
            sB[k4 + 0][m] = w.x; sB[k4 + 1][m] = w.y;
            sB[k4 + 2][m] = w.z; sB[k4 + 3][m] = w.w;
        }
        __syncthreads();
        #pragma unroll
        for (int kk = 0; kk < 64; ++kk) {
            float4 a = *reinterpret_cast<const float4*>(&sA[kk][ty << 2]);
            float4 b = *reinterpret_cast<const float4*>(&sB[kk][tx << 2]);
            float av[4] = {a.x, a.y, a.z, a.w};
            float bv[4] = {b.x, b.y, b.z, b.w};
            #pragma unroll
            for (int i = 0; i < 4; ++i)
                #pragma unroll
                for (int j = 0; j < 4; ++j)
                    acc[i][j] = fmaf(av[i], bv[j], acc[i][j]);
        }
        __syncthreads();
    }
    #pragma unroll
    for (int i = 0; i < 4; ++i) {
        long m = bm + (ty << 2) + i;
        #pragma unroll
        for (int j = 0; j < 4; ++j) {
            int n = bn + (tx << 2) + j;
            C[m * N + n] = acc[i][j] + bias[n];
        }
    }
}

__global__ __launch_bounds__(256) void score_argmax(const float* __restrict__ z,
                                                    const float* __restrict__ embed,
                                                    const float* __restrict__ esq,
                                                    int* __restrict__ idx_out,
                                                    float* __restrict__ idx_f32) {
    __shared__ __align__(16) float sZ[64][68];
    __shared__ __align__(16) float sE[64][68];
    const int tid = threadIdx.x;
    const int tx = tid & 15, ty = tid >> 4;
    const int bm = blockIdx.x << 6;
    float best[4];
    int bidx[4];
    #pragma unroll
    for (int i = 0; i < 4; ++i) { best[i] = -3.4e38f; bidx[i] = 0; }
    for (int ct = 0; ct < CBS; ct += 64) {
        float acc[4][4] = {};
        for (int k0 = 0; k0 < CBD; k0 += 64) {
            #pragma unroll
            for (int i = 0; i < 4; ++i) {
                int f = tid + (i << 8);
                int m = f >> 4;
                int k4 = (f & 15) << 2;
                float4 v = *reinterpret_cast<const float4*>(z + (long)(bm + m) * CBD + k0 + k4);
                sZ[k4 + 0][m] = v.x; sZ[k4 + 1][m] = v.y;
                sZ[k4 + 2][m] = v.z; sZ[k4 + 3][m] = v.w;
                float4 w = *reinterpret_cast<const float4*>(embed + (long)(ct + m) * CBD + k0 + k4);
                sE[k4 + 0][m] = w.x; sE[k4 + 1][m] = w.y;
                sE[k4 + 2][m] = w.z; sE[k4 + 3][m] = w.w;
            }
            __syncthreads();
            #pragma unroll
            for (int kk = 0; kk < 64; ++kk) {
                float4 a = *reinterpret_cast<const float4*>(&sZ[kk][ty << 2]);
                float4 b = *reinterpret_cast<const float4*>(&sE[kk][tx << 2]);
                float av[4] = {a.x, a.y, a.z, a.w};
                float bv[4] = {b.x, b.y, b.z, b.w};
                #pragma unroll
                for (int i = 0; i < 4; ++i)
                    #pragma unroll
                    for (int j = 0; j < 4; ++j)
                        acc[i][j] = fmaf(av[i], bv[j], acc[i][j]);
            }
            __syncthreads();
        }
        #pragma unroll
        for (int j = 0; j < 4; ++j) {
            int c = ct + (tx << 2) + j;
            float eq = esq[c];
            #pragma unroll
            for (int i = 0; i < 4; ++i) {
                float s = 2.0f * acc[i][j] - eq;
                if (s > best[i] || (s == best[i] && c < bidx[i])) { best[i] = s; bidx[i] = c; }
            }
        }
    }
    #pragma unroll
    for (int i = 0; i < 4; ++i) {
        float b = best[i];
        int bi = bidx[i];
        #pragma unroll
        for (int m = 1; m < 16; m <<= 1) {
            float ob = __shfl_xor(b, m, 64);
            int oi = __shfl_xor(bi, m, 64);
            if (ob > b || (ob == b && oi < bi)) { b = ob; bi = oi; }
        }
        if (tx == 0) {
            int row = bm + (ty << 2) + i;
            idx_out[row] = bi;
            idx_f32[row] = (float)bi;
        }
    }
}

extern "C" void kernel_launch(void* const* d_in, const int* in_sizes, int n_in,
                              void* d_out, int out_size, void* d_ws, size_t ws_size,
                              hipStream_t stream) {
    const float* x     = (const float*)d_in[0];
    const float* embed = (const float*)d_in[1];
    const float* W_in  = (const float*)d_in[2];
    const float* b_in  = (const float*)d_in[3];
    const float* W_out = (const float*)d_in[4];
    const float* b_out = (const float*)d_in[5];

    float* out_idx = (float*)d_out;              // [16384] indices as float
    float* out     = (float*)d_out + N_TOK;      // [16384,512]

    // workspace layout (main path). partials aliases xpack (dead after gemm_in).
    char* ws = (char*)d_ws;
    float*  esq      = (float*)ws;                                   // 32KB
    float*  rescueT  = (float*)(ws + 32768);                         // 64KB
    int*    idx      = (int*)(ws + 98304);                           // 64KB
    float2* znorm2   = (float2*)(ws + 163840);                       // 128KB
    float*  denorm   = (float*)(ws + 294912);                        // 32KB
    float*  maxe     = (float*)(ws + 327680);                        // 256B
    short*  xpack    = (short*)(ws + 327936);                        // 33.55MB
    float4* partials = (float4*)(ws + 327936);                       // 8MB (alias)
    float*  zf32     = (float*)(ws + 327936 + 33554432);             // 16.78MB
    short*  z16      = (short*)((char*)zf32 + 16777216);             // 8.39MB
    short*  e16      = z16 + (size_t)N_TOK * 256;                    // 4.19MB
    short*  epack    = e16 + (size_t)CBS * 256;                      // 8.39MB
    short*  winpk    = epack + (size_t)CBS * 512;                    // 0.52MB
    short*  wopk     = winpk + (size_t)CBD * 1024;                   // 0.52MB
    size_t need = (size_t)((char*)(wopk + (size_t)DIM * 512) - ws);

    if (ws_size >= need) {
        pack_w<9><<<(N_TOK * DIM) / 256, 256, 0, stream>>>(x, xpack);
        pack_w<9><<<(CBD * DIM) / 256, 256, 0, stream>>>(W_in, winpk);
        pack_w<8><<<(DIM * CBD) / 256, 256, 0, stream>>>(W_out, wopk);
        prep_embed<<<CBS / 4, 256, 0, stream>>>(embed, esq, epack, e16, denorm);
        maxe_k<<<1, 256, 0, stream>>>(esq, denorm, maxe);
        // z = x@W_in^T + b_in (4-term MFMA) -> z16 (f16) + zf32 (exact)
        gemm_in_mfma<<<dim3(N_TOK / 64, 2), 256, 0, stream>>>(xpack, winpk, b_in, z16, zf32);
        znorm_k<<<N_TOK / 4, 256, 0, stream>>>(zf32, z16, znorm2);
        // fp16 1-term scores + per-tile top-2
        score_mfma<<<2048, 512, 0, stream>>>(z16, e16, esq, partials);
        // combine -> idx + measured-norm rescue thresholds
        combine<<<N_TOK / 8, 256, 0, stream>>>(partials, znorm2, maxe, idx, out_idx, rescueT);
        // exact rescue (zf32-based; coalesced 16-lane-per-code scan)
        rescue<<<N_TOK, 256, 0, stream>>>(zf32, embed, esq, partials, rescueT, idx, out_idx);
        // out = embed[idx]@W_out^T + b_out
        gemm_out_mfma<<<dim3(N_TOK / 128, 4), 256, 0, stream>>>(epack, wopk, idx, b_out, out);
    } else {
        float* z   = (float*)d_ws;
        float* es  = z + (size_t)N_TOK * CBD;
        int*   id  = (int*)(es + CBS);
        gemm_nt<false><<<dim3(N_TOK / 64, CBD / 64), 256, 0, stream>>>(
            x, W_in, b_in, nullptr, z, N_TOK, CBD, DIM);
        esq_kernel<<<CBS / 4, 256, 0, stream>>>(embed, es);
        score_argmax<<<N_TOK / 64, 256, 0, stream>>>(z, embed, es, id, out_idx);
        gemm_nt<true><<<dim3(N_TOK / 64, DIM / 64), 256, 0, stream>>>(
            embed, W_out, b_out, id, out, N_TOK, DIM, CBD);
    }
}